// Round 3
// baseline (547.729 us; speedup 1.0000x reference)
//
#include <hip/hip_runtime.h>

#define NN 100000
#define NE 1600000
#define F 128
#define NBUCK ((NN + 255) >> 8)                         // 391 buckets of 256 nodes
#define SCAT_BLOCKS 512
#define EPB (NE / SCAT_BLOCKS)                          // 3125 edges per scatter block
#define IDX_CAP 1536                                    // LDS csr-slice capacity (mean 1024, sd ~32)

typedef _Float16 f16x8 __attribute__((ext_vector_type(8)));
typedef float    f32x4 __attribute__((ext_vector_type(4)));
typedef unsigned short ushort8v __attribute__((ext_vector_type(8)));
typedef unsigned short ushort4v __attribute__((ext_vector_type(4)));

__device__ inline unsigned short f2h(float f) {
    _Float16 h = (_Float16)f;                       // RTN
    return __builtin_bit_cast(unsigned short, h);
}
__device__ inline float h2f(unsigned short u) {
    return (float)__builtin_bit_cast(_Float16, u);
}

// ---------------- CSR build (bucket-level binning, LDS-staged coalesced writes) ----------------
__global__ __launch_bounds__(256) void k_bhist(const int* __restrict__ dst, int* __restrict__ bcnt) {
    __shared__ int sc[NBUCK];
    for (int i = threadIdx.x; i < NBUCK; i += 256) sc[i] = 0;
    __syncthreads();
    int stride = gridDim.x * 256;
    for (int e = blockIdx.x * 256 + threadIdx.x; e < NE; e += stride)
        atomicAdd(&sc[dst[e] >> 8], 1);
    __syncthreads();
    for (int i = threadIdx.x; i < NBUCK; i += 256) {
        int c = sc[i];
        if (c) atomicAdd(&bcnt[i], c);
    }
}

__global__ void k_bscan(const int* __restrict__ bcnt, int* __restrict__ bbase, int* __restrict__ bcur) {
    __shared__ int s[512];
    int t = threadIdx.x;
    int v = (t < NBUCK) ? bcnt[t] : 0;
    s[t] = v;
    __syncthreads();
    for (int off = 1; off < 512; off <<= 1) {
        int u = (t >= off) ? s[t - off] : 0;
        __syncthreads();
        s[t] += u;
        __syncthreads();
    }
    int excl = s[t] - v;
    if (t < NBUCK) { bbase[t] = excl; bcur[t] = excl; }
    if (t == 0) bbase[NBUCK] = NE;
}

__global__ __launch_bounds__(256) void k_scatterA(const int* __restrict__ src,
                                                  const int* __restrict__ dst,
                                                  int* __restrict__ bcur,
                                                  unsigned* __restrict__ scratch) {
    __shared__ uint2 sEdge[EPB];          // 25 KB
    __shared__ int cnt[512];
    __shared__ int scn[512];
    __shared__ int cntB[512];
    __shared__ int gbase[512];
    __shared__ int ssum[256];

    const int tid = threadIdx.x;
    const int ebase = blockIdx.x * EPB;

#pragma unroll
    for (int i = tid; i < 512; i += 256) { cnt[i] = 0; cntB[i] = 0; }
    __syncthreads();

    for (int i = tid; i < EPB; i += 256) {
        int b = dst[ebase + i] >> 8;
        atomicAdd(&cnt[b], 1);
    }
    __syncthreads();

    int c0 = cnt[2 * tid], c1 = cnt[2 * tid + 1];
    ssum[tid] = c0 + c1;
    __syncthreads();
    for (int off = 1; off < 256; off <<= 1) {
        int v = (tid >= off) ? ssum[tid - off] : 0;
        __syncthreads();
        ssum[tid] += v;
        __syncthreads();
    }
    int texcl = (tid == 0) ? 0 : ssum[tid - 1];
    scn[2 * tid] = texcl;
    scn[2 * tid + 1] = texcl + c0;
#pragma unroll
    for (int i = tid; i < NBUCK; i += 256) {
        int c = cnt[i];
        gbase[i] = c ? atomicAdd(&bcur[i], c) : 0;
    }
    __syncthreads();

    for (int i = tid; i < EPB; i += 256) {
        int s = src[ebase + i], d = dst[ebase + i];
        int b = d >> 8;
        int rank = atomicAdd(&cntB[b], 1);
        sEdge[scn[b] + rank] = make_uint2((unsigned)s, (unsigned)d);
    }
    __syncthreads();

    for (int i = tid; i < EPB; i += 256) {
        uint2 ed = sEdge[i];
        int b = (int)(ed.y >> 8);
        unsigned w = ((ed.y & 255u) << 24) | ed.x;
        scratch[gbase[b] + (i - scn[b])] = w;
    }
}

__global__ __launch_bounds__(256) void k_fillB(const int* __restrict__ bbase,
                                               const unsigned* __restrict__ scratch,
                                               int* __restrict__ row_ptr,
                                               int* __restrict__ csr) {
    __shared__ int cnt[256];
    __shared__ int s[256];
    __shared__ int cur[256];
    int b = blockIdx.x;
    int base = bbase[b], end = bbase[b + 1];
    int t = threadIdx.x;
    cnt[t] = 0;
    __syncthreads();
    for (int i = base + t; i < end; i += 256)
        atomicAdd(&cnt[scratch[i] >> 24], 1);
    __syncthreads();
    int v = cnt[t];
    s[t] = v;
    __syncthreads();
    for (int off = 1; off < 256; off <<= 1) {
        int u = (t >= off) ? s[t - off] : 0;
        __syncthreads();
        s[t] += u;
        __syncthreads();
    }
    int excl = s[t] - v;
    int node = (b << 8) + t;
    if (node < NN) row_ptr[node] = base + excl;
    if (b == NBUCK - 1 && t == 0) row_ptr[NN] = NE;
    cur[t] = excl;
    __syncthreads();
    for (int i = base + t; i < end; i += 256) {
        unsigned w = scratch[i];
        int n = w >> 24;
        int p = atomicAdd(&cur[n], 1);
        csr[base + p] = (int)(w & 0xFFFFFFu);
    }
}

// ---------------- x -> fp16 (RTN), row-major ----------------
__global__ void k_x2h(const float* __restrict__ x, unsigned short* __restrict__ xh) {
    int idx = blockIdx.x * 256 + threadIdx.x;     // over float4s, NN*128/4 total
    float4 v = ((const float4*)x)[idx];
    ushort4v h;
    h.x = f2h(v.x);
    h.y = f2h(v.y);
    h.z = f2h(v.z);
    h.w = f2h(v.w);
    ((ushort4v*)xh)[idx] = h;
}

// ---------------- weight: W[k][n] fp32 -> Wt [n][k] fp16 ----------------
struct WPack {
    const float* w[5];
    unsigned short* t[5];
};

__global__ void k_w2h(WPack p) {
    int which = blockIdx.x >> 6;
    int idx = (blockIdx.x & 63) * 256 + threadIdx.x; // over n*128+k
    int n = idx >> 7, k = idx & 127;
    p.t[which][idx] = f2h(p.w[which][k * 128 + n]);
}

// ---------------- single-row chunk accumulation (indices from LDS or global) ----------------
template <bool LOC>
__device__ __forceinline__ void accum1(float a[8], int st, int e,
                                       const int* __restrict__ sIdx,
                                       const int* __restrict__ gIdx,
                                       const unsigned short* __restrict__ G,
                                       int lofs) {
    int p = st;
    for (; p + 4 <= e; p += 4) {
        int j0 = LOC ? sIdx[p]     : gIdx[p];
        int j1 = LOC ? sIdx[p + 1] : gIdx[p + 1];
        int j2 = LOC ? sIdx[p + 2] : gIdx[p + 2];
        int j3 = LOC ? sIdx[p + 3] : gIdx[p + 3];
        ushort8v v0 = *(const ushort8v*)&G[(size_t)j0 * F + lofs];
        ushort8v v1 = *(const ushort8v*)&G[(size_t)j1 * F + lofs];
        ushort8v v2 = *(const ushort8v*)&G[(size_t)j2 * F + lofs];
        ushort8v v3 = *(const ushort8v*)&G[(size_t)j3 * F + lofs];
#pragma unroll
        for (int k = 0; k < 8; ++k)
            a[k] += (h2f(v0[k]) + h2f(v1[k])) + (h2f(v2[k]) + h2f(v3[k]));
    }
    for (; p < e; ++p) {
        int j0 = LOC ? sIdx[p] : gIdx[p];
        ushort8v v0 = *(const ushort8v*)&G[(size_t)j0 * F + lofs];
#pragma unroll
        for (int k = 0; k < 8; ++k) a[k] += h2f(v0[k]);
    }
}

// ---------------- aggregation, column-sliced & XCD-pinned ----------------
// grid = 1563 tiles x 4 chunks, bid = tile*4 + c.  HW round-robins bid%8 -> XCD,
// so chunk c only runs on XCDs {c, c+4}: each 64B line-column of G is touched by
// 2 XCDs instead of 8 (compulsory fetch 165MB -> ~51MB) and stays L2-resident.
// 4-lane groups own one dst row: 4 x 16B = the row's full 64B chunk (1 line).
__global__ __launch_bounds__(256, 8) void k_agg(const unsigned short* __restrict__ G,
                                                const int* __restrict__ row_ptr,
                                                const int* __restrict__ csr,
                                                unsigned short* __restrict__ AGG) {
    __shared__ int sRP[65];
    __shared__ int sIdx[IDX_CAP];                        // 6 KB

    const int tid  = threadIdx.x;
    const int tile = blockIdx.x >> 2;
    const int c    = blockIdx.x & 3;
    const int row0 = tile * 64;

    if (tid < 65) {
        int n = row0 + tid;
        if (n > NN) n = NN;
        sRP[tid] = row_ptr[n];
    }
    __syncthreads();
    const int ibase = sRP[0];
    const int icnt  = sRP[64] - ibase;
    const int icap  = icnt < IDX_CAP ? icnt : IDX_CAP;
    for (int i = tid; i < icap; i += 256) sIdx[i] = csr[ibase + i];
    __syncthreads();

    const int g    = tid >> 2;           // 0..63 : dst row within tile
    const int l4   = tid & 3;
    const int lofs = c * 32 + l4 * 8;    // this lane's 8 fp16 cols
    const int node = row0 + g;
    if (node >= NN) return;

    float a[8];
    ushort8v sh = *(const ushort8v*)&G[(size_t)node * F + lofs];
#pragma unroll
    for (int k = 0; k < 8; ++k) a[k] = h2f(sh[k]);

    int st = sRP[g] - ibase, e = sRP[g + 1] - ibase;
    if (e <= icap)
        accum1<true>(a, st, e, sIdx, csr + ibase, G, lofs);
    else
        accum1<false>(a, st, e, sIdx, csr + ibase, G, lofs);

    ushort8v o;
#pragma unroll
    for (int k = 0; k < 8; ++k) o[k] = f2h(a[k]);
    *(ushort8v*)&AGG[(size_t)node * F + lofs] = o;
}

// ---------------- MLP over aggregated rows: sA load + 2-GEMM (or GEMM1+dot) ----------------
template <int L3>
__global__ __launch_bounds__(256, 6) void k_mlp(const unsigned short* __restrict__ AGG,
                                                const unsigned short* __restrict__ W1,
                                                const float* __restrict__ b1,
                                                const unsigned short* __restrict__ W2,
                                                const float* __restrict__ b2,
                                                const float* __restrict__ w32,
                                                const float* __restrict__ b32,
                                                unsigned short* __restrict__ H,
                                                float* __restrict__ out) {
    __shared__ __align__(16) unsigned short sA[64 * 128];   // 16 KB

    const int tid = threadIdx.x;
    const int row0 = blockIdx.x * 64;
    const int cg   = tid >> 6;           // wave id = col slice 0..3
    const int lane = tid & 63;
    const int m16  = lane & 15;
    const int quad = lane >> 4;

    // ---- stage AGG tile -> swizzled sA (coalesced 16B/lane) ----
#pragma unroll
    for (int i = 0; i < 4; ++i) {
        int fg = i * 256 + tid;
        int r = fg >> 4, u = fg & 15;
        ushort8v v = {};
        if (row0 + r < NN)
            v = *(const ushort8v*)&AGG[(size_t)row0 * F + fg * 8];
        *(ushort8v*)&sA[r * 128 + ((u ^ (r & 15)) << 3)] = v;
    }
    __syncthreads();

    // ---- GEMM1 (4 col-slice waves, 32 cols each) ----
    f32x4 acc[4][2] = {};
#pragma unroll
    for (int ks = 0; ks < 4; ++ks) {
        f16x8 a[4];
#pragma unroll
        for (int rt = 0; rt < 4; ++rt) {
            int rowL = rt * 16 + m16;
            int u = ks * 4 + quad;
            a[rt] = *(const f16x8*)&sA[rowL * 128 + ((u ^ (rowL & 15)) << 3)];
        }
#pragma unroll
        for (int ct = 0; ct < 2; ++ct) {
            int widx = (cg * 32 + ct * 16 + m16) * 128 + ks * 32 + quad * 8;
            f16x8 b = *(const f16x8*)&W1[widx];
#pragma unroll
            for (int rt = 0; rt < 4; ++rt)
                acc[rt][ct] = __builtin_amdgcn_mfma_f32_16x16x32_f16(a[rt], b, acc[rt][ct], 0, 0, 0);
        }
    }

    if (L3) {
        float* psf = (float*)sA;     // 64 rows x 4 cg
        __syncthreads();
#pragma unroll
        for (int rt = 0; rt < 4; ++rt) {
            float s[4] = {0.f, 0.f, 0.f, 0.f};
#pragma unroll
            for (int ct = 0; ct < 2; ++ct) {
                int col = cg * 32 + ct * 16 + m16;
                float bv = b1[col];
                float wv = w32[col];
#pragma unroll
                for (int i = 0; i < 4; ++i) {
                    float v = fmaxf(acc[rt][ct][i] + bv, 0.f);
                    s[i] += v * wv;
                }
            }
#pragma unroll
            for (int i = 0; i < 4; ++i) {
#pragma unroll
                for (int mask = 1; mask < 16; mask <<= 1)
                    s[i] += __shfl_xor(s[i], mask, 64);
            }
            if (m16 == 0) {
#pragma unroll
                for (int i = 0; i < 4; ++i) {
                    int rowL = rt * 16 + quad * 4 + i;
                    psf[rowL * 4 + cg] = s[i];
                }
            }
        }
        __syncthreads();
        if (tid < 64) {
            int row = row0 + tid;
            if (row < NN)
                out[row] = (psf[tid * 4] + psf[tid * 4 + 1]) + (psf[tid * 4 + 2] + psf[tid * 4 + 3]) + b32[0];
        }
        return;
    }

    // ---- h1 = relu(acc+b1) -> fp16 into LDS col-slice (C-layout -> A-layout) ----
    __syncthreads();
#pragma unroll
    for (int rt = 0; rt < 4; ++rt) {
#pragma unroll
        for (int ct = 0; ct < 2; ++ct) {
            int col = cg * 32 + ct * 16 + m16;
            float bv = b1[col];
#pragma unroll
            for (int i = 0; i < 4; ++i) {
                int rL = rt * 16 + quad * 4 + i;
                float v = fmaxf(acc[rt][ct][i] + bv, 0.f);
                sA[rL * 128 + (((col >> 3) ^ (rL & 15)) << 3) + (col & 7)] = f2h(v);
            }
        }
    }
    __syncthreads();

    // ---- GEMM2 ----
    f32x4 acc2[4][2] = {};
#pragma unroll
    for (int ks = 0; ks < 4; ++ks) {
        f16x8 a[4];
#pragma unroll
        for (int rt = 0; rt < 4; ++rt) {
            int rowL = rt * 16 + m16;
            int u = ks * 4 + quad;
            a[rt] = *(const f16x8*)&sA[rowL * 128 + ((u ^ (rowL & 15)) << 3)];
        }
#pragma unroll
        for (int ct = 0; ct < 2; ++ct) {
            int widx = (cg * 32 + ct * 16 + m16) * 128 + ks * 32 + quad * 8;
            f16x8 b = *(const f16x8*)&W2[widx];
#pragma unroll
            for (int rt = 0; rt < 4; ++rt)
                acc2[rt][ct] = __builtin_amdgcn_mfma_f32_16x16x32_f16(a[rt], b, acc2[rt][ct], 0, 0, 0);
        }
    }

    // ---- epilogue: bias -> fp16 -> LDS -> coalesced row-major store ----
    __syncthreads();
#pragma unroll
    for (int rt = 0; rt < 4; ++rt) {
#pragma unroll
        for (int ct = 0; ct < 2; ++ct) {
            int col = cg * 32 + ct * 16 + m16;
            float bv = b2[col];
#pragma unroll
            for (int i = 0; i < 4; ++i) {
                int rL = rt * 16 + quad * 4 + i;
                float v = acc2[rt][ct][i] + bv;
                sA[rL * 128 + (((col >> 3) ^ (rL & 15)) << 3) + (col & 7)] = f2h(v);
            }
        }
    }
    __syncthreads();
    {
        ushort8v* go = (ushort8v*)(H + (size_t)row0 * F);
#pragma unroll
        for (int i = 0; i < 4; ++i) {
            int fg = i * 256 + tid;
            int r = fg >> 4, u = fg & 15;
            if (row0 + r < NN)
                go[fg] = *(const ushort8v*)&sA[r * 128 + ((u ^ (r & 15)) << 3)];
        }
    }
}

// ---------------- launch ----------------
static inline size_t align256(size_t x) { return (x + 255) & ~(size_t)255; }

extern "C" void kernel_launch(void* const* d_in, const int* in_sizes, int n_in,
                              void* d_out, int out_size, void* d_ws, size_t ws_size,
                              hipStream_t stream) {
    const float* x   = (const float*)d_in[0];
    const int*   ei  = (const int*)d_in[1];
    const float* w11 = (const float*)d_in[2];
    const float* b11 = (const float*)d_in[3];
    const float* w12 = (const float*)d_in[4];
    const float* b12 = (const float*)d_in[5];
    const float* w21 = (const float*)d_in[6];
    const float* b21 = (const float*)d_in[7];
    const float* w22 = (const float*)d_in[8];
    const float* b22 = (const float*)d_in[9];
    const float* w31 = (const float*)d_in[10];
    const float* b31 = (const float*)d_in[11];
    const float* w32 = (const float*)d_in[12];
    const float* b32 = (const float*)d_in[13];
    float* out = (float*)d_out;

    const int* src = ei;
    const int* dst = ei + NE;

    char* ws = (char*)d_ws;
    size_t off = 0;
    unsigned short* Abuf = (unsigned short*)(ws + off); off += align256((size_t)NN * F * 2);
    unsigned short* Bbuf = (unsigned short*)(ws + off); off += align256((size_t)NN * F * 2);
    unsigned short* AGG  = (unsigned short*)(ws + off); off += align256((size_t)NN * F * 2);
    int* bcnt    = (int*)(ws + off); off += align256((size_t)NBUCK * 4);
    int* bbase   = (int*)(ws + off); off += align256((size_t)(NBUCK + 1) * 4);
    int* bcur    = (int*)(ws + off); off += align256((size_t)NBUCK * 4);
    int* row_ptr = (int*)(ws + off); off += align256((size_t)(NN + 1) * 4);
    int* csr     = (int*)(ws + off); off += align256((size_t)NE * 4);
    unsigned* scratch = (unsigned*)(ws + off); off += align256((size_t)NE * 4);
    unsigned short* wt[5];
    for (int i = 0; i < 5; ++i) {
        wt[i] = (unsigned short*)(ws + off); off += align256((size_t)128 * 128 * 2);
    }
    (void)ws_size;

    // ---- weight + input conversion ----
    WPack wp;
    wp.w[0] = w11; wp.w[1] = w12; wp.w[2] = w21; wp.w[3] = w22; wp.w[4] = w31;
    for (int i = 0; i < 5; ++i) wp.t[i] = wt[i];
    k_w2h<<<320, 256, 0, stream>>>(wp);
    k_x2h<<<(NN * F / 4 + 255) / 256, 256, 0, stream>>>(x, Abuf);

    // ---- CSR build (bucket-level) ----
    (void)hipMemsetAsync(bcnt, 0, (size_t)NBUCK * 4, stream);
    k_bhist<<<256, 256, 0, stream>>>(dst, bcnt);
    k_bscan<<<1, 512, 0, stream>>>(bcnt, bbase, bcur);
    k_scatterA<<<SCAT_BLOCKS, 256, 0, stream>>>(src, dst, bcur, scratch);
    k_fillB<<<NBUCK, 256, 0, stream>>>(bbase, scratch, row_ptr, csr);

    const int tiles = (NN + 63) / 64;           // 1563
    const int aggBlocks = tiles * 4;            // 6252, bid%8 -> XCD pinning

    // ---- layer 1: Abuf -> AGG -> Bbuf ----
    k_agg<<<aggBlocks, 256, 0, stream>>>(Abuf, row_ptr, csr, AGG);
    k_mlp<0><<<tiles, 256, 0, stream>>>(AGG, wt[0], b11, wt[1], b12,
                                        nullptr, nullptr, Bbuf, nullptr);
    // ---- layer 2: Bbuf -> AGG -> Abuf ----
    k_agg<<<aggBlocks, 256, 0, stream>>>(Bbuf, row_ptr, csr, AGG);
    k_mlp<0><<<tiles, 256, 0, stream>>>(AGG, wt[2], b21, wt[3], b22,
                                        nullptr, nullptr, Abuf, nullptr);
    // ---- layer 3: Abuf -> AGG -> out ----
    k_agg<<<aggBlocks, 256, 0, stream>>>(Abuf, row_ptr, csr, AGG);
    k_mlp<1><<<tiles, 256, 0, stream>>>(AGG, wt[4], b31, nullptr, nullptr,
                                        w32, b32, nullptr, out);
}

// Round 4
// 473.140 us; speedup vs baseline: 1.1576x; 1.1576x over previous
//
#include <hip/hip_runtime.h>

#define NN 100000
#define NE 1600000
#define F 128
#define NBUCK ((NN + 255) >> 8)                         // 391 buckets of 256 nodes
#define SCAT_BLOCKS 512
#define EPB (NE / SCAT_BLOCKS)                          // 3125 edges per scatter block
#define TROWS 128                                       // dst rows per k_agg tile
#define NTILE ((NN + TROWS - 1) / TROWS)                // 782
#define IDX_CAP2 2816                                   // mean 2048, sd ~45 -> 17 sigma

typedef _Float16 f16x8 __attribute__((ext_vector_type(8)));
typedef float    f32x4 __attribute__((ext_vector_type(4)));
typedef unsigned short ushort8v __attribute__((ext_vector_type(8)));
typedef unsigned short ushort4v __attribute__((ext_vector_type(4)));

__device__ inline unsigned short f2h(float f) {
    _Float16 h = (_Float16)f;                       // RTN
    return __builtin_bit_cast(unsigned short, h);
}
__device__ inline float h2f(unsigned short u) {
    return (float)__builtin_bit_cast(_Float16, u);
}

// ---------------- CSR build (bucket-level binning, LDS-staged coalesced writes) ----------------
__global__ __launch_bounds__(256) void k_bhist(const int* __restrict__ dst, int* __restrict__ bcnt) {
    __shared__ int sc[NBUCK];
    for (int i = threadIdx.x; i < NBUCK; i += 256) sc[i] = 0;
    __syncthreads();
    int stride = gridDim.x * 256;
    for (int e = blockIdx.x * 256 + threadIdx.x; e < NE; e += stride)
        atomicAdd(&sc[dst[e] >> 8], 1);
    __syncthreads();
    for (int i = threadIdx.x; i < NBUCK; i += 256) {
        int c = sc[i];
        if (c) atomicAdd(&bcnt[i], c);
    }
}

__global__ void k_bscan(const int* __restrict__ bcnt, int* __restrict__ bbase, int* __restrict__ bcur) {
    __shared__ int s[512];
    int t = threadIdx.x;
    int v = (t < NBUCK) ? bcnt[t] : 0;
    s[t] = v;
    __syncthreads();
    for (int off = 1; off < 512; off <<= 1) {
        int u = (t >= off) ? s[t - off] : 0;
        __syncthreads();
        s[t] += u;
        __syncthreads();
    }
    int excl = s[t] - v;
    if (t < NBUCK) { bbase[t] = excl; bcur[t] = excl; }
    if (t == 0) bbase[NBUCK] = NE;
}

__global__ __launch_bounds__(256) void k_scatterA(const int* __restrict__ src,
                                                  const int* __restrict__ dst,
                                                  int* __restrict__ bcur,
                                                  unsigned* __restrict__ scratch) {
    __shared__ uint2 sEdge[EPB];          // 25 KB
    __shared__ int cnt[512];
    __shared__ int scn[512];
    __shared__ int cntB[512];
    __shared__ int gbase[512];
    __shared__ int ssum[256];

    const int tid = threadIdx.x;
    const int ebase = blockIdx.x * EPB;

#pragma unroll
    for (int i = tid; i < 512; i += 256) { cnt[i] = 0; cntB[i] = 0; }
    __syncthreads();

    for (int i = tid; i < EPB; i += 256) {
        int b = dst[ebase + i] >> 8;
        atomicAdd(&cnt[b], 1);
    }
    __syncthreads();

    int c0 = cnt[2 * tid], c1 = cnt[2 * tid + 1];
    ssum[tid] = c0 + c1;
    __syncthreads();
    for (int off = 1; off < 256; off <<= 1) {
        int v = (tid >= off) ? ssum[tid - off] : 0;
        __syncthreads();
        ssum[tid] += v;
        __syncthreads();
    }
    int texcl = (tid == 0) ? 0 : ssum[tid - 1];
    scn[2 * tid] = texcl;
    scn[2 * tid + 1] = texcl + c0;
#pragma unroll
    for (int i = tid; i < NBUCK; i += 256) {
        int c = cnt[i];
        gbase[i] = c ? atomicAdd(&bcur[i], c) : 0;
    }
    __syncthreads();

    for (int i = tid; i < EPB; i += 256) {
        int s = src[ebase + i], d = dst[ebase + i];
        int b = d >> 8;
        int rank = atomicAdd(&cntB[b], 1);
        sEdge[scn[b] + rank] = make_uint2((unsigned)s, (unsigned)d);
    }
    __syncthreads();

    for (int i = tid; i < EPB; i += 256) {
        uint2 ed = sEdge[i];
        int b = (int)(ed.y >> 8);
        unsigned w = ((ed.y & 255u) << 24) | ed.x;
        scratch[gbase[b] + (i - scn[b])] = w;
    }
}

__global__ __launch_bounds__(256) void k_fillB(const int* __restrict__ bbase,
                                               const unsigned* __restrict__ scratch,
                                               int* __restrict__ row_ptr,
                                               int* __restrict__ csr) {
    __shared__ int cnt[256];
    __shared__ int s[256];
    __shared__ int cur[256];
    int b = blockIdx.x;
    int base = bbase[b], end = bbase[b + 1];
    int t = threadIdx.x;
    cnt[t] = 0;
    __syncthreads();
    for (int i = base + t; i < end; i += 256)
        atomicAdd(&cnt[scratch[i] >> 24], 1);
    __syncthreads();
    int v = cnt[t];
    s[t] = v;
    __syncthreads();
    for (int off = 1; off < 256; off <<= 1) {
        int u = (t >= off) ? s[t - off] : 0;
        __syncthreads();
        s[t] += u;
        __syncthreads();
    }
    int excl = s[t] - v;
    int node = (b << 8) + t;
    if (node < NN) row_ptr[node] = base + excl;
    if (b == NBUCK - 1 && t == 0) row_ptr[NN] = NE;
    cur[t] = excl;
    __syncthreads();
    for (int i = base + t; i < end; i += 256) {
        unsigned w = scratch[i];
        int n = w >> 24;
        int p = atomicAdd(&cur[n], 1);
        csr[base + p] = (int)(w & 0xFFFFFFu);
    }
}

// ---------------- x (row-major fp32) -> G chunk-major fp16 [8][NN][16] ----------------
// thread (j, c): reads one full 64B line x[j*128 + c*16 .. +16), writes 32B contiguous chunk.
__global__ __launch_bounds__(256) void k_x2h(const float* __restrict__ x, unsigned short* __restrict__ xh) {
    int j = blockIdx.x * 256 + threadIdx.x;
    int c = blockIdx.y;
    if (j >= NN) return;
    const float4* px = (const float4*)&x[(size_t)j * F + c * 16];
    float4 v0 = px[0], v1 = px[1], v2 = px[2], v3 = px[3];
    ushort8v h0, h1;
    h0[0] = f2h(v0.x); h0[1] = f2h(v0.y); h0[2] = f2h(v0.z); h0[3] = f2h(v0.w);
    h0[4] = f2h(v1.x); h0[5] = f2h(v1.y); h0[6] = f2h(v1.z); h0[7] = f2h(v1.w);
    h1[0] = f2h(v2.x); h1[1] = f2h(v2.y); h1[2] = f2h(v2.z); h1[3] = f2h(v2.w);
    h1[4] = f2h(v3.x); h1[5] = f2h(v3.y); h1[6] = f2h(v3.z); h1[7] = f2h(v3.w);
    unsigned short* o = &xh[((size_t)c * NN + j) * 16];
    *(ushort8v*)o = h0;
    *(ushort8v*)(o + 8) = h1;
}

// ---------------- weight: W[k][n] fp32 -> Wt [n][k] fp16 ----------------
struct WPack {
    const float* w[5];
    unsigned short* t[5];
};

__global__ void k_w2h(WPack p) {
    int which = blockIdx.x >> 6;
    int idx = (blockIdx.x & 63) * 256 + threadIdx.x; // over n*128+k
    int n = idx >> 7, k = idx & 127;
    p.t[which][idx] = f2h(p.w[which][k * 128 + n]);
}

// ---------------- single-row chunk accumulation over chunk-major column Gc[NN][16] ----------------
template <bool LOC>
__device__ __forceinline__ void accum1(float a[8], int st, int e,
                                       const int* __restrict__ sIdx,
                                       const int* __restrict__ gIdx,
                                       const unsigned short* __restrict__ Gc,
                                       int lofs) {
    int p = st;
    for (; p + 4 <= e; p += 4) {
        int j0 = LOC ? sIdx[p]     : gIdx[p];
        int j1 = LOC ? sIdx[p + 1] : gIdx[p + 1];
        int j2 = LOC ? sIdx[p + 2] : gIdx[p + 2];
        int j3 = LOC ? sIdx[p + 3] : gIdx[p + 3];
        ushort8v v0 = *(const ushort8v*)&Gc[(size_t)j0 * 16 + lofs];
        ushort8v v1 = *(const ushort8v*)&Gc[(size_t)j1 * 16 + lofs];
        ushort8v v2 = *(const ushort8v*)&Gc[(size_t)j2 * 16 + lofs];
        ushort8v v3 = *(const ushort8v*)&Gc[(size_t)j3 * 16 + lofs];
#pragma unroll
        for (int k = 0; k < 8; ++k)
            a[k] += (h2f(v0[k]) + h2f(v1[k])) + (h2f(v2[k]) + h2f(v3[k]));
    }
    for (; p < e; ++p) {
        int j0 = LOC ? sIdx[p] : gIdx[p];
        ushort8v v0 = *(const ushort8v*)&Gc[(size_t)j0 * 16 + lofs];
#pragma unroll
        for (int k = 0; k < 8; ++k) a[k] += h2f(v0[k]);
    }
}

// ---------------- aggregation: chunk-major columns, 1 chunk per XCD ----------------
// G layout [8][NN][16] fp16: chunk column = contiguous 3.2 MB < 4 MB per-XCD L2.
// grid = NTILE tiles x 8 chunks, bid = tile*8 + c -> bid%8 = c pins column c to XCD c.
// 2 lanes per dst row (2 x 16B = the 32B chunk), 128-row tiles.
__global__ __launch_bounds__(256, 8) void k_agg(const unsigned short* __restrict__ G,
                                                const int* __restrict__ row_ptr,
                                                const int* __restrict__ csr,
                                                unsigned short* __restrict__ AGG) {
    __shared__ int sRP[TROWS + 1];
    __shared__ int sIdx[IDX_CAP2];                       // 11 KB

    const int tid  = threadIdx.x;
    const int tile = blockIdx.x >> 3;
    const int c    = blockIdx.x & 7;
    const int row0 = tile * TROWS;
    const unsigned short* Gc = G   + (size_t)c * NN * 16;
    unsigned short*       Ac = AGG + (size_t)c * NN * 16;

    if (tid < TROWS + 1) {
        int n = row0 + tid;
        if (n > NN) n = NN;
        sRP[tid] = row_ptr[n];
    }
    __syncthreads();
    const int ibase = sRP[0];
    const int icnt  = sRP[TROWS] - ibase;
    const int icap  = icnt < IDX_CAP2 ? icnt : IDX_CAP2;
    for (int i = tid; i < icap; i += 256) sIdx[i] = csr[ibase + i];
    __syncthreads();

    const int g    = tid >> 1;           // 0..127 : dst row within tile
    const int lofs = (tid & 1) * 8;      // this lane's 8 fp16 within the 16-col chunk
    const int node = row0 + g;
    if (node >= NN) return;

    float a[8];
    ushort8v sh = *(const ushort8v*)&Gc[(size_t)node * 16 + lofs];
#pragma unroll
    for (int k = 0; k < 8; ++k) a[k] = h2f(sh[k]);

    int st = sRP[g] - ibase, e = sRP[g + 1] - ibase;
    if (e <= icap)
        accum1<true>(a, st, e, sIdx, csr + ibase, Gc, lofs);
    else
        accum1<false>(a, st, e, sIdx, csr + ibase, Gc, lofs);

    ushort8v o;
#pragma unroll
    for (int k = 0; k < 8; ++k) o[k] = f2h(a[k]);
    *(ushort8v*)&Ac[(size_t)node * 16 + lofs] = o;
}

// ---------------- MLP over aggregated rows (chunk-major input/output) ----------------
template <int L3>
__global__ __launch_bounds__(256, 6) void k_mlp(const unsigned short* __restrict__ AGG,
                                                const unsigned short* __restrict__ W1,
                                                const float* __restrict__ b1,
                                                const unsigned short* __restrict__ W2,
                                                const float* __restrict__ b2,
                                                const float* __restrict__ w32,
                                                const float* __restrict__ b32,
                                                unsigned short* __restrict__ H,
                                                float* __restrict__ out) {
    __shared__ __align__(16) unsigned short sA[64 * 128];   // 16 KB

    const int tid = threadIdx.x;
    const int row0 = blockIdx.x * 64;
    const int cg   = tid >> 6;           // wave id = col slice 0..3
    const int lane = tid & 63;
    const int m16  = lane & 15;
    const int quad = lane >> 4;

    // ---- stage AGG (chunk-major [8][NN][16]) tile -> swizzled sA ----
#pragma unroll
    for (int i = 0; i < 4; ++i) {
        int unit = i * 256 + tid;        // 0..1023 : 16B units
        int c    = unit >> 7;            // chunk
        int idx  = unit & 127;
        int node = idx >> 1;
        int h    = idx & 1;
        ushort8v v = {};
        if (row0 + node < NN)
            v = *(const ushort8v*)&AGG[((size_t)c * NN + row0 + node) * 16 + h * 8];
        int u = c * 2 + h;               // 16B-unit col 0..15
        *(ushort8v*)&sA[node * 128 + ((u ^ (node & 15)) << 3)] = v;
    }
    __syncthreads();

    // ---- GEMM1 (4 col-slice waves, 32 cols each) ----
    f32x4 acc[4][2] = {};
#pragma unroll
    for (int ks = 0; ks < 4; ++ks) {
        f16x8 a[4];
#pragma unroll
        for (int rt = 0; rt < 4; ++rt) {
            int rowL = rt * 16 + m16;
            int u = ks * 4 + quad;
            a[rt] = *(const f16x8*)&sA[rowL * 128 + ((u ^ (rowL & 15)) << 3)];
        }
#pragma unroll
        for (int ct = 0; ct < 2; ++ct) {
            int widx = (cg * 32 + ct * 16 + m16) * 128 + ks * 32 + quad * 8;
            f16x8 b = *(const f16x8*)&W1[widx];
#pragma unroll
            for (int rt = 0; rt < 4; ++rt)
                acc[rt][ct] = __builtin_amdgcn_mfma_f32_16x16x32_f16(a[rt], b, acc[rt][ct], 0, 0, 0);
        }
    }

    if (L3) {
        float* psf = (float*)sA;     // 64 rows x 4 cg
        __syncthreads();
#pragma unroll
        for (int rt = 0; rt < 4; ++rt) {
            float s[4] = {0.f, 0.f, 0.f, 0.f};
#pragma unroll
            for (int ct = 0; ct < 2; ++ct) {
                int col = cg * 32 + ct * 16 + m16;
                float bv = b1[col];
                float wv = w32[col];
#pragma unroll
                for (int i = 0; i < 4; ++i) {
                    float v = fmaxf(acc[rt][ct][i] + bv, 0.f);
                    s[i] += v * wv;
                }
            }
#pragma unroll
            for (int i = 0; i < 4; ++i) {
#pragma unroll
                for (int mask = 1; mask < 16; mask <<= 1)
                    s[i] += __shfl_xor(s[i], mask, 64);
            }
            if (m16 == 0) {
#pragma unroll
                for (int i = 0; i < 4; ++i) {
                    int rowL = rt * 16 + quad * 4 + i;
                    psf[rowL * 4 + cg] = s[i];
                }
            }
        }
        __syncthreads();
        if (tid < 64) {
            int row = row0 + tid;
            if (row < NN)
                out[row] = (psf[tid * 4] + psf[tid * 4 + 1]) + (psf[tid * 4 + 2] + psf[tid * 4 + 3]) + b32[0];
        }
        return;
    }

    // ---- h1 = relu(acc+b1) -> fp16 into LDS col-slice (C-layout -> A-layout) ----
    __syncthreads();
#pragma unroll
    for (int rt = 0; rt < 4; ++rt) {
#pragma unroll
        for (int ct = 0; ct < 2; ++ct) {
            int col = cg * 32 + ct * 16 + m16;
            float bv = b1[col];
#pragma unroll
            for (int i = 0; i < 4; ++i) {
                int rL = rt * 16 + quad * 4 + i;
                float v = fmaxf(acc[rt][ct][i] + bv, 0.f);
                sA[rL * 128 + (((col >> 3) ^ (rL & 15)) << 3) + (col & 7)] = f2h(v);
            }
        }
    }
    __syncthreads();

    // ---- GEMM2 ----
    f32x4 acc2[4][2] = {};
#pragma unroll
    for (int ks = 0; ks < 4; ++ks) {
        f16x8 a[4];
#pragma unroll
        for (int rt = 0; rt < 4; ++rt) {
            int rowL = rt * 16 + m16;
            int u = ks * 4 + quad;
            a[rt] = *(const f16x8*)&sA[rowL * 128 + ((u ^ (rowL & 15)) << 3)];
        }
#pragma unroll
        for (int ct = 0; ct < 2; ++ct) {
            int widx = (cg * 32 + ct * 16 + m16) * 128 + ks * 32 + quad * 8;
            f16x8 b = *(const f16x8*)&W2[widx];
#pragma unroll
            for (int rt = 0; rt < 4; ++rt)
                acc2[rt][ct] = __builtin_amdgcn_mfma_f32_16x16x32_f16(a[rt], b, acc2[rt][ct], 0, 0, 0);
        }
    }

    // ---- epilogue: bias -> fp16 -> LDS -> chunk-major contiguous store ----
    __syncthreads();
#pragma unroll
    for (int rt = 0; rt < 4; ++rt) {
#pragma unroll
        for (int ct = 0; ct < 2; ++ct) {
            int col = cg * 32 + ct * 16 + m16;
            float bv = b2[col];
#pragma unroll
            for (int i = 0; i < 4; ++i) {
                int rL = rt * 16 + quad * 4 + i;
                float v = acc2[rt][ct][i] + bv;
                sA[rL * 128 + (((col >> 3) ^ (rL & 15)) << 3) + (col & 7)] = f2h(v);
            }
        }
    }
    __syncthreads();
    {
#pragma unroll
        for (int i = 0; i < 4; ++i) {
            int unit = i * 256 + tid;
            int c    = unit >> 7;
            int idx  = unit & 127;
            int node = idx >> 1;
            int h    = idx & 1;
            int u    = c * 2 + h;
            if (row0 + node < NN)
                *(ushort8v*)&H[((size_t)c * NN + row0 + node) * 16 + h * 8] =
                    *(const ushort8v*)&sA[node * 128 + ((u ^ (node & 15)) << 3)];
        }
    }
}

// ---------------- launch ----------------
static inline size_t align256(size_t x) { return (x + 255) & ~(size_t)255; }

extern "C" void kernel_launch(void* const* d_in, const int* in_sizes, int n_in,
                              void* d_out, int out_size, void* d_ws, size_t ws_size,
                              hipStream_t stream) {
    const float* x   = (const float*)d_in[0];
    const int*   ei  = (const int*)d_in[1];
    const float* w11 = (const float*)d_in[2];
    const float* b11 = (const float*)d_in[3];
    const float* w12 = (const float*)d_in[4];
    const float* b12 = (const float*)d_in[5];
    const float* w21 = (const float*)d_in[6];
    const float* b21 = (const float*)d_in[7];
    const float* w22 = (const float*)d_in[8];
    const float* b22 = (const float*)d_in[9];
    const float* w31 = (const float*)d_in[10];
    const float* b31 = (const float*)d_in[11];
    const float* w32 = (const float*)d_in[12];
    const float* b32 = (const float*)d_in[13];
    float* out = (float*)d_out;

    const int* src = ei;
    const int* dst = ei + NE;

    char* ws = (char*)d_ws;
    size_t off = 0;
    unsigned short* Abuf = (unsigned short*)(ws + off); off += align256((size_t)NN * F * 2);
    unsigned short* Bbuf = (unsigned short*)(ws + off); off += align256((size_t)NN * F * 2);
    unsigned short* AGG  = (unsigned short*)(ws + off); off += align256((size_t)NN * F * 2);
    int* bcnt    = (int*)(ws + off); off += align256((size_t)NBUCK * 4);
    int* bbase   = (int*)(ws + off); off += align256((size_t)(NBUCK + 1) * 4);
    int* bcur    = (int*)(ws + off); off += align256((size_t)NBUCK * 4);
    int* row_ptr = (int*)(ws + off); off += align256((size_t)(NN + 1) * 4);
    int* csr     = (int*)(ws + off); off += align256((size_t)NE * 4);
    unsigned* scratch = (unsigned*)(ws + off); off += align256((size_t)NE * 4);
    unsigned short* wt[5];
    for (int i = 0; i < 5; ++i) {
        wt[i] = (unsigned short*)(ws + off); off += align256((size_t)128 * 128 * 2);
    }
    (void)ws_size;

    // ---- weight + input conversion ----
    WPack wp;
    wp.w[0] = w11; wp.w[1] = w12; wp.w[2] = w21; wp.w[3] = w22; wp.w[4] = w31;
    for (int i = 0; i < 5; ++i) wp.t[i] = wt[i];
    k_w2h<<<320, 256, 0, stream>>>(wp);
    {
        dim3 gx((NN + 255) / 256, 8);
        k_x2h<<<gx, 256, 0, stream>>>(x, Abuf);
    }

    // ---- CSR build (bucket-level) ----
    (void)hipMemsetAsync(bcnt, 0, (size_t)NBUCK * 4, stream);
    k_bhist<<<256, 256, 0, stream>>>(dst, bcnt);
    k_bscan<<<1, 512, 0, stream>>>(bcnt, bbase, bcur);
    k_scatterA<<<SCAT_BLOCKS, 256, 0, stream>>>(src, dst, bcur, scratch);
    k_fillB<<<NBUCK, 256, 0, stream>>>(bbase, scratch, row_ptr, csr);

    const int mlpTiles = (NN + 63) / 64;        // 1563
    const int aggBlocks = NTILE * 8;            // 6256, bid%8 = chunk -> XCD

    // ---- layer 1: Abuf -> AGG -> Bbuf ----
    k_agg<<<aggBlocks, 256, 0, stream>>>(Abuf, row_ptr, csr, AGG);
    k_mlp<0><<<mlpTiles, 256, 0, stream>>>(AGG, wt[0], b11, wt[1], b12,
                                           nullptr, nullptr, Bbuf, nullptr);
    // ---- layer 2: Bbuf -> AGG -> Abuf ----
    k_agg<<<aggBlocks, 256, 0, stream>>>(Bbuf, row_ptr, csr, AGG);
    k_mlp<0><<<mlpTiles, 256, 0, stream>>>(AGG, wt[2], b21, wt[3], b22,
                                           nullptr, nullptr, Abuf, nullptr);
    // ---- layer 3: Abuf -> AGG -> out ----
    k_agg<<<aggBlocks, 256, 0, stream>>>(Abuf, row_ptr, csr, AGG);
    k_mlp<1><<<mlpTiles, 256, 0, stream>>>(AGG, wt[4], b31, nullptr, nullptr,
                                           w32, b32, nullptr, out);
}

// Round 5
// 464.318 us; speedup vs baseline: 1.1796x; 1.0190x over previous
//
#include <hip/hip_runtime.h>

#define NN 100000
#define NE 1600000
#define F 128
#define HALFN 50000
#define NBUCK ((NN + 255) >> 8)                         // 391 buckets of 256 nodes
#define SCAT_BLOCKS 512
#define EPB (NE / SCAT_BLOCKS)                          // 3125 edges per scatter block
#define TROWS 64                                        // dst rows per k_agg tile
#define NTILE ((NN + TROWS - 1) / TROWS)                // 1563
#define IDX_CAP 1536                                    // mean 1024, sd ~32

typedef _Float16 f16x8 __attribute__((ext_vector_type(8)));
typedef float    f32x4 __attribute__((ext_vector_type(4)));
typedef unsigned short ushort8v __attribute__((ext_vector_type(8)));
typedef unsigned short ushort4v __attribute__((ext_vector_type(4)));

__device__ inline unsigned short f2h(float f) {
    _Float16 h = (_Float16)f;                       // RTN
    return __builtin_bit_cast(unsigned short, h);
}
__device__ inline float h2f(unsigned short u) {
    return (float)__builtin_bit_cast(_Float16, u);
}

// ---------------- CSR build (bucket-level binning, LDS-staged coalesced writes) ----------------
__global__ __launch_bounds__(256) void k_bhist(const int* __restrict__ dst, int* __restrict__ bcnt) {
    __shared__ int sc[NBUCK];
    for (int i = threadIdx.x; i < NBUCK; i += 256) sc[i] = 0;
    __syncthreads();
    int stride = gridDim.x * 256;
    for (int e = blockIdx.x * 256 + threadIdx.x; e < NE; e += stride)
        atomicAdd(&sc[dst[e] >> 8], 1);
    __syncthreads();
    for (int i = threadIdx.x; i < NBUCK; i += 256) {
        int c = sc[i];
        if (c) atomicAdd(&bcnt[i], c);
    }
}

__global__ void k_bscan(const int* __restrict__ bcnt, int* __restrict__ bbase, int* __restrict__ bcur) {
    __shared__ int s[512];
    int t = threadIdx.x;
    int v = (t < NBUCK) ? bcnt[t] : 0;
    s[t] = v;
    __syncthreads();
    for (int off = 1; off < 512; off <<= 1) {
        int u = (t >= off) ? s[t - off] : 0;
        __syncthreads();
        s[t] += u;
        __syncthreads();
    }
    int excl = s[t] - v;
    if (t < NBUCK) { bbase[t] = excl; bcur[t] = excl; }
    if (t == 0) bbase[NBUCK] = NE;
}

__global__ __launch_bounds__(256) void k_scatterA(const int* __restrict__ src,
                                                  const int* __restrict__ dst,
                                                  int* __restrict__ bcur,
                                                  unsigned* __restrict__ scratch) {
    __shared__ uint2 sEdge[EPB];          // 25 KB
    __shared__ int cnt[512];
    __shared__ int scn[512];
    __shared__ int cntB[512];
    __shared__ int gbase[512];
    __shared__ int ssum[256];

    const int tid = threadIdx.x;
    const int ebase = blockIdx.x * EPB;

#pragma unroll
    for (int i = tid; i < 512; i += 256) { cnt[i] = 0; cntB[i] = 0; }
    __syncthreads();

    for (int i = tid; i < EPB; i += 256) {
        int b = dst[ebase + i] >> 8;
        atomicAdd(&cnt[b], 1);
    }
    __syncthreads();

    int c0 = cnt[2 * tid], c1 = cnt[2 * tid + 1];
    ssum[tid] = c0 + c1;
    __syncthreads();
    for (int off = 1; off < 256; off <<= 1) {
        int v = (tid >= off) ? ssum[tid - off] : 0;
        __syncthreads();
        ssum[tid] += v;
        __syncthreads();
    }
    int texcl = (tid == 0) ? 0 : ssum[tid - 1];
    scn[2 * tid] = texcl;
    scn[2 * tid + 1] = texcl + c0;
#pragma unroll
    for (int i = tid; i < NBUCK; i += 256) {
        int c = cnt[i];
        gbase[i] = c ? atomicAdd(&bcur[i], c) : 0;
    }
    __syncthreads();

    for (int i = tid; i < EPB; i += 256) {
        int s = src[ebase + i], d = dst[ebase + i];
        int b = d >> 8;
        int rank = atomicAdd(&cntB[b], 1);
        sEdge[scn[b] + rank] = make_uint2((unsigned)s, (unsigned)d);
    }
    __syncthreads();

    for (int i = tid; i < EPB; i += 256) {
        uint2 ed = sEdge[i];
        int b = (int)(ed.y >> 8);
        unsigned w = ((ed.y & 255u) << 24) | ed.x;
        scratch[gbase[b] + (i - scn[b])] = w;
    }
}

__global__ __launch_bounds__(256) void k_fillB(const int* __restrict__ bbase,
                                               const unsigned* __restrict__ scratch,
                                               int* __restrict__ row_ptr,
                                               int* __restrict__ csr) {
    __shared__ int cnt[256];
    __shared__ int s[256];
    __shared__ int cur[256];
    int b = blockIdx.x;
    int base = bbase[b], end = bbase[b + 1];
    int t = threadIdx.x;
    cnt[t] = 0;
    __syncthreads();
    for (int i = base + t; i < end; i += 256)
        atomicAdd(&cnt[scratch[i] >> 24], 1);
    __syncthreads();
    int v = cnt[t];
    s[t] = v;
    __syncthreads();
    for (int off = 1; off < 256; off <<= 1) {
        int u = (t >= off) ? s[t - off] : 0;
        __syncthreads();
        s[t] += u;
        __syncthreads();
    }
    int excl = s[t] - v;
    int node = (b << 8) + t;
    if (node < NN) row_ptr[node] = base + excl;
    if (b == NBUCK - 1 && t == 0) row_ptr[NN] = NE;
    cur[t] = excl;
    __syncthreads();
    for (int i = base + t; i < end; i += 256) {
        unsigned w = scratch[i];
        int n = w >> 24;
        int p = atomicAdd(&cur[n], 1);
        csr[base + p] = (int)(w & 0xFFFFFFu);
    }
}

// ---------------- x (row-major fp32) -> G chunk-major fp16 [4][NN][32] ----------------
// thread (j, c): reads 128B of row j, writes one full 64B line (node j's chunk c).
__global__ __launch_bounds__(256) void k_x2h(const float* __restrict__ x, unsigned short* __restrict__ xh) {
    int j = blockIdx.x * 256 + threadIdx.x;
    int c = blockIdx.y;
    if (j >= NN) return;
    const float4* px = (const float4*)&x[(size_t)j * F + c * 32];
    unsigned short* o = &xh[((size_t)c * NN + j) * 32];
#pragma unroll
    for (int half = 0; half < 4; ++half) {
        float4 v0 = px[half * 2], v1 = px[half * 2 + 1];
        ushort8v h;
        h[0] = f2h(v0.x); h[1] = f2h(v0.y); h[2] = f2h(v0.z); h[3] = f2h(v0.w);
        h[4] = f2h(v1.x); h[5] = f2h(v1.y); h[6] = f2h(v1.z); h[7] = f2h(v1.w);
        *(ushort8v*)(o + half * 8) = h;
    }
}

// ---------------- weight: W[k][n] fp32 -> Wt [n][k] fp16 ----------------
struct WPack {
    const float* w[5];
    unsigned short* t[5];
};

__global__ void k_w2h(WPack p) {
    int which = blockIdx.x >> 6;
    int idx = (blockIdx.x & 63) * 256 + threadIdx.x; // over n*128+k
    int n = idx >> 7, k = idx & 127;
    p.t[which][idx] = f2h(p.w[which][k * 128 + n]);
}

// ---------------- half-filtered accumulation over chunk column Gc[NN][32] ----------------
// Pre-zeroed regs + exec-masked loads (no use in branch -> 4 loads in flight), then acc.
template <bool LOC>
__device__ __forceinline__ void accum_half(float a[8], int st, int e,
                                           const int* __restrict__ sIdx,
                                           const int* __restrict__ gIdx,
                                           const unsigned short* __restrict__ Gc,
                                           int lofs, bool hb) {
    int p = st;
    for (; p + 4 <= e; p += 4) {
        int j0 = LOC ? sIdx[p]     : gIdx[p];
        int j1 = LOC ? sIdx[p + 1] : gIdx[p + 1];
        int j2 = LOC ? sIdx[p + 2] : gIdx[p + 2];
        int j3 = LOC ? sIdx[p + 3] : gIdx[p + 3];
        ushort8v v0 = {}, v1 = {}, v2 = {}, v3 = {};
        if ((j0 >= HALFN) == hb) v0 = *(const ushort8v*)&Gc[(size_t)j0 * 32 + lofs];
        if ((j1 >= HALFN) == hb) v1 = *(const ushort8v*)&Gc[(size_t)j1 * 32 + lofs];
        if ((j2 >= HALFN) == hb) v2 = *(const ushort8v*)&Gc[(size_t)j2 * 32 + lofs];
        if ((j3 >= HALFN) == hb) v3 = *(const ushort8v*)&Gc[(size_t)j3 * 32 + lofs];
#pragma unroll
        for (int k = 0; k < 8; ++k)
            a[k] += (h2f(v0[k]) + h2f(v1[k])) + (h2f(v2[k]) + h2f(v3[k]));
    }
    for (; p < e; ++p) {
        int j0 = LOC ? sIdx[p] : gIdx[p];
        if ((j0 >= HALFN) == hb) {
            ushort8v v0 = *(const ushort8v*)&Gc[(size_t)j0 * 32 + lofs];
#pragma unroll
            for (int k = 0; k < 8; ++k) a[k] += h2f(v0[k]);
        }
    }
}

// ---------------- aggregation: full-line chunks + src-half split, XCD-pinned ----------------
// G layout [4][NN][32] fp16 (64B = 1 line per node per chunk).  Block class cc = h*4+c
// (bid%8 -> XCD): chunk c, src-half h.  Per-XCD working set = 50K x 64B = 3.2MB < 4MB L2.
// Each edge: 4 blocks x 1 full line = 6.4M line transactions (halved vs 32B chunks).
// Partials PART[h*4+c][NN][32] written unconditionally; k_mlp sums the two halves.
__global__ __launch_bounds__(256, 8) void k_agg(const unsigned short* __restrict__ G,
                                                const int* __restrict__ row_ptr,
                                                const int* __restrict__ csr,
                                                unsigned short* __restrict__ PART) {
    __shared__ int sRP[TROWS + 1];
    __shared__ int sIdx[IDX_CAP];                        // 6 KB

    const int tid  = threadIdx.x;
    const int tile = blockIdx.x >> 3;
    const int cc   = blockIdx.x & 7;
    const int c    = cc & 3;
    const bool hb  = (cc >> 2) != 0;
    const int row0 = tile * TROWS;
    const unsigned short* Gc = G + (size_t)c * NN * 32;

    if (tid < TROWS + 1) {
        int n = row0 + tid;
        if (n > NN) n = NN;
        sRP[tid] = row_ptr[n];
    }
    __syncthreads();
    const int ibase = sRP[0];
    const int icnt  = sRP[TROWS] - ibase;
    const int icap  = icnt < IDX_CAP ? icnt : IDX_CAP;
    for (int i = tid; i < icap; i += 256) sIdx[i] = csr[ibase + i];
    __syncthreads();

    const int g    = tid >> 2;           // 0..63 : dst row within tile
    const int lofs = (tid & 3) * 8;      // this lane's 8 fp16 within the 32-col chunk
    const int node = row0 + g;
    if (node >= NN) return;

    float a[8] = {};
    if ((node >= HALFN) == hb) {         // self term lives in the node's own half
        ushort8v sh = *(const ushort8v*)&Gc[(size_t)node * 32 + lofs];
#pragma unroll
        for (int k = 0; k < 8; ++k) a[k] = h2f(sh[k]);
    }

    int st = sRP[g] - ibase, e = sRP[g + 1] - ibase;
    if (e <= icap)
        accum_half<true>(a, st, e, sIdx, csr + ibase, Gc, lofs, hb);
    else
        accum_half<false>(a, st, e, sIdx, csr + ibase, Gc, lofs, hb);

    ushort8v o;
#pragma unroll
    for (int k = 0; k < 8; ++k) o[k] = f2h(a[k]);
    *(ushort8v*)&PART[((size_t)cc * NN + node) * 32 + lofs] = o;
}

// ---------------- MLP: stage (PART[0]+PART[1]) -> sA, 2-GEMM (or GEMM1+dot) ----------------
template <int L3>
__global__ __launch_bounds__(256, 6) void k_mlp(const unsigned short* __restrict__ PART,
                                                const unsigned short* __restrict__ W1,
                                                const float* __restrict__ b1,
                                                const unsigned short* __restrict__ W2,
                                                const float* __restrict__ b2,
                                                const float* __restrict__ w32,
                                                const float* __restrict__ b32,
                                                unsigned short* __restrict__ H,
                                                float* __restrict__ out) {
    __shared__ __align__(16) unsigned short sA[64 * 128];   // 16 KB

    const int tid = threadIdx.x;
    const int row0 = blockIdx.x * 64;
    const int cg   = tid >> 6;           // wave id = col slice 0..3
    const int lane = tid & 63;
    const int m16  = lane & 15;
    const int quad = lane >> 4;
    const size_t H1OFF = (size_t)4 * NN * 32;    // PART half-1 base

    // ---- stage sum of halves (chunk-major [4][NN][32]) -> swizzled sA ----
#pragma unroll
    for (int i = 0; i < 4; ++i) {
        int unit = i * 256 + tid;        // 0..1023 : 16B units
        int c    = unit >> 8;            // chunk 0..3
        int idx  = unit & 255;
        int node = idx >> 2;
        int q    = idx & 3;
        ushort8v o = {};
        if (row0 + node < NN) {
            size_t base = ((size_t)c * NN + row0 + node) * 32 + q * 8;
            ushort8v v0 = *(const ushort8v*)&PART[base];
            ushort8v v1 = *(const ushort8v*)&PART[H1OFF + base];
#pragma unroll
            for (int k = 0; k < 8; ++k) o[k] = f2h(h2f(v0[k]) + h2f(v1[k]));
        }
        int u = c * 4 + q;               // 16B-unit col 0..15
        *(ushort8v*)&sA[node * 128 + ((u ^ (node & 15)) << 3)] = o;
    }
    __syncthreads();

    // ---- GEMM1 (4 col-slice waves, 32 cols each) ----
    f32x4 acc[4][2] = {};
#pragma unroll
    for (int ks = 0; ks < 4; ++ks) {
        f16x8 a[4];
#pragma unroll
        for (int rt = 0; rt < 4; ++rt) {
            int rowL = rt * 16 + m16;
            int u = ks * 4 + quad;
            a[rt] = *(const f16x8*)&sA[rowL * 128 + ((u ^ (rowL & 15)) << 3)];
        }
#pragma unroll
        for (int ct = 0; ct < 2; ++ct) {
            int widx = (cg * 32 + ct * 16 + m16) * 128 + ks * 32 + quad * 8;
            f16x8 b = *(const f16x8*)&W1[widx];
#pragma unroll
            for (int rt = 0; rt < 4; ++rt)
                acc[rt][ct] = __builtin_amdgcn_mfma_f32_16x16x32_f16(a[rt], b, acc[rt][ct], 0, 0, 0);
        }
    }

    if (L3) {
        float* psf = (float*)sA;     // 64 rows x 4 cg
        __syncthreads();
#pragma unroll
        for (int rt = 0; rt < 4; ++rt) {
            float s[4] = {0.f, 0.f, 0.f, 0.f};
#pragma unroll
            for (int ct = 0; ct < 2; ++ct) {
                int col = cg * 32 + ct * 16 + m16;
                float bv = b1[col];
                float wv = w32[col];
#pragma unroll
                for (int i = 0; i < 4; ++i) {
                    float v = fmaxf(acc[rt][ct][i] + bv, 0.f);
                    s[i] += v * wv;
                }
            }
#pragma unroll
            for (int i = 0; i < 4; ++i) {
#pragma unroll
                for (int mask = 1; mask < 16; mask <<= 1)
                    s[i] += __shfl_xor(s[i], mask, 64);
            }
            if (m16 == 0) {
#pragma unroll
                for (int i = 0; i < 4; ++i) {
                    int rowL = rt * 16 + quad * 4 + i;
                    psf[rowL * 4 + cg] = s[i];
                }
            }
        }
        __syncthreads();
        if (tid < 64) {
            int row = row0 + tid;
            if (row < NN)
                out[row] = (psf[tid * 4] + psf[tid * 4 + 1]) + (psf[tid * 4 + 2] + psf[tid * 4 + 3]) + b32[0];
        }
        return;
    }

    // ---- h1 = relu(acc+b1) -> fp16 into LDS col-slice (C-layout -> A-layout) ----
    __syncthreads();
#pragma unroll
    for (int rt = 0; rt < 4; ++rt) {
#pragma unroll
        for (int ct = 0; ct < 2; ++ct) {
            int col = cg * 32 + ct * 16 + m16;
            float bv = b1[col];
#pragma unroll
            for (int i = 0; i < 4; ++i) {
                int rL = rt * 16 + quad * 4 + i;
                float v = fmaxf(acc[rt][ct][i] + bv, 0.f);
                sA[rL * 128 + (((col >> 3) ^ (rL & 15)) << 3) + (col & 7)] = f2h(v);
            }
        }
    }
    __syncthreads();

    // ---- GEMM2 ----
    f32x4 acc2[4][2] = {};
#pragma unroll
    for (int ks = 0; ks < 4; ++ks) {
        f16x8 a[4];
#pragma unroll
        for (int rt = 0; rt < 4; ++rt) {
            int rowL = rt * 16 + m16;
            int u = ks * 4 + quad;
            a[rt] = *(const f16x8*)&sA[rowL * 128 + ((u ^ (rowL & 15)) << 3)];
        }
#pragma unroll
        for (int ct = 0; ct < 2; ++ct) {
            int widx = (cg * 32 + ct * 16 + m16) * 128 + ks * 32 + quad * 8;
            f16x8 b = *(const f16x8*)&W2[widx];
#pragma unroll
            for (int rt = 0; rt < 4; ++rt)
                acc2[rt][ct] = __builtin_amdgcn_mfma_f32_16x16x32_f16(a[rt], b, acc2[rt][ct], 0, 0, 0);
        }
    }

    // ---- epilogue: bias -> fp16 -> LDS -> chunk-major contiguous store ----
    __syncthreads();
#pragma unroll
    for (int rt = 0; rt < 4; ++rt) {
#pragma unroll
        for (int ct = 0; ct < 2; ++ct) {
            int col = cg * 32 + ct * 16 + m16;
            float bv = b2[col];
#pragma unroll
            for (int i = 0; i < 4; ++i) {
                int rL = rt * 16 + quad * 4 + i;
                float v = acc2[rt][ct][i] + bv;
                sA[rL * 128 + (((col >> 3) ^ (rL & 15)) << 3) + (col & 7)] = f2h(v);
            }
        }
    }
    __syncthreads();
    {
#pragma unroll
        for (int i = 0; i < 4; ++i) {
            int unit = i * 256 + tid;
            int c    = unit >> 8;
            int idx  = unit & 255;
            int node = idx >> 2;
            int q    = idx & 3;
            int u    = c * 4 + q;
            if (row0 + node < NN)
                *(ushort8v*)&H[((size_t)c * NN + row0 + node) * 32 + q * 8] =
                    *(const ushort8v*)&sA[node * 128 + ((u ^ (node & 15)) << 3)];
        }
    }
}

// ---------------- launch ----------------
static inline size_t align256(size_t x) { return (x + 255) & ~(size_t)255; }

extern "C" void kernel_launch(void* const* d_in, const int* in_sizes, int n_in,
                              void* d_out, int out_size, void* d_ws, size_t ws_size,
                              hipStream_t stream) {
    const float* x   = (const float*)d_in[0];
    const int*   ei  = (const int*)d_in[1];
    const float* w11 = (const float*)d_in[2];
    const float* b11 = (const float*)d_in[3];
    const float* w12 = (const float*)d_in[4];
    const float* b12 = (const float*)d_in[5];
    const float* w21 = (const float*)d_in[6];
    const float* b21 = (const float*)d_in[7];
    const float* w22 = (const float*)d_in[8];
    const float* b22 = (const float*)d_in[9];
    const float* w31 = (const float*)d_in[10];
    const float* b31 = (const float*)d_in[11];
    const float* w32 = (const float*)d_in[12];
    const float* b32 = (const float*)d_in[13];
    float* out = (float*)d_out;

    const int* src = ei;
    const int* dst = ei + NE;

    char* ws = (char*)d_ws;
    size_t off = 0;
    unsigned short* Abuf = (unsigned short*)(ws + off); off += align256((size_t)NN * F * 2);
    unsigned short* Bbuf = (unsigned short*)(ws + off); off += align256((size_t)NN * F * 2);
    unsigned short* PART = (unsigned short*)(ws + off); off += align256((size_t)NN * F * 2 * 2);  // 2 halves
    int* bcnt    = (int*)(ws + off); off += align256((size_t)NBUCK * 4);
    int* bbase   = (int*)(ws + off); off += align256((size_t)(NBUCK + 1) * 4);
    int* bcur    = (int*)(ws + off); off += align256((size_t)NBUCK * 4);
    int* row_ptr = (int*)(ws + off); off += align256((size_t)(NN + 1) * 4);
    int* csr     = (int*)(ws + off); off += align256((size_t)NE * 4);
    unsigned* scratch = (unsigned*)(ws + off); off += align256((size_t)NE * 4);
    unsigned short* wt[5];
    for (int i = 0; i < 5; ++i) {
        wt[i] = (unsigned short*)(ws + off); off += align256((size_t)128 * 128 * 2);
    }
    (void)ws_size;

    // ---- weight + input conversion ----
    WPack wp;
    wp.w[0] = w11; wp.w[1] = w12; wp.w[2] = w21; wp.w[3] = w22; wp.w[4] = w31;
    for (int i = 0; i < 5; ++i) wp.t[i] = wt[i];
    k_w2h<<<320, 256, 0, stream>>>(wp);
    {
        dim3 gx((NN + 255) / 256, 4);
        k_x2h<<<gx, 256, 0, stream>>>(x, Abuf);
    }

    // ---- CSR build (bucket-level) ----
    (void)hipMemsetAsync(bcnt, 0, (size_t)NBUCK * 4, stream);
    k_bhist<<<512, 256, 0, stream>>>(dst, bcnt);
    k_bscan<<<1, 512, 0, stream>>>(bcnt, bbase, bcur);
    k_scatterA<<<SCAT_BLOCKS, 256, 0, stream>>>(src, dst, bcur, scratch);
    k_fillB<<<NBUCK, 256, 0, stream>>>(bbase, scratch, row_ptr, csr);

    const int mlpTiles = (NN + 63) / 64;        // 1563
    const int aggBlocks = NTILE * 8;            // 12504, bid%8 = class -> XCD

    // ---- layer 1: Abuf -> PART -> Bbuf ----
    k_agg<<<aggBlocks, 256, 0, stream>>>(Abuf, row_ptr, csr, PART);
    k_mlp<0><<<mlpTiles, 256, 0, stream>>>(PART, wt[0], b11, wt[1], b12,
                                           nullptr, nullptr, Bbuf, nullptr);
    // ---- layer 2: Bbuf -> PART -> Abuf ----
    k_agg<<<aggBlocks, 256, 0, stream>>>(Bbuf, row_ptr, csr, PART);
    k_mlp<0><<<mlpTiles, 256, 0, stream>>>(PART, wt[2], b21, wt[3], b22,
                                           nullptr, nullptr, Abuf, nullptr);
    // ---- layer 3: Abuf -> PART -> out ----
    k_agg<<<aggBlocks, 256, 0, stream>>>(Abuf, row_ptr, csr, PART);
    k_mlp<1><<<mlpTiles, 256, 0, stream>>>(PART, wt[4], b31, nullptr, nullptr,
                                           w32, b32, nullptr, out);
}

// Round 6
// 432.850 us; speedup vs baseline: 1.2654x; 1.0727x over previous
//
#include <hip/hip_runtime.h>

#define NN 100000
#define NE 1600000
#define F 128
#define HALFN 50000
#define NBUCK ((NN + 255) >> 8)                         // 391 buckets of 256 nodes
#define SCAT_BLOCKS 512
#define EPB (NE / SCAT_BLOCKS)                          // 3125 edges per scatter block
#define TROWS 64                                        // dst rows per k_agg tile
#define NTILE ((NN + TROWS - 1) / TROWS)                // 1563
#define IDX_CAP 1536                                    // mean 1024, sd ~32

typedef _Float16 f16x8 __attribute__((ext_vector_type(8)));
typedef float    f32x4 __attribute__((ext_vector_type(4)));
typedef unsigned short ushort8v __attribute__((ext_vector_type(8)));
typedef unsigned short ushort4v __attribute__((ext_vector_type(4)));

__device__ inline unsigned short f2h(float f) {
    _Float16 h = (_Float16)f;                       // RTN
    return __builtin_bit_cast(unsigned short, h);
}
__device__ inline float h2f(unsigned short u) {
    return (float)__builtin_bit_cast(_Float16, u);
}

// ---------------- CSR build (bucket-level binning, LDS-staged coalesced writes) ----------------
__global__ __launch_bounds__(256) void k_bhist(const int* __restrict__ dst, int* __restrict__ bcnt) {
    __shared__ int sc[NBUCK];
    for (int i = threadIdx.x; i < NBUCK; i += 256) sc[i] = 0;
    __syncthreads();
    int stride = gridDim.x * 256;
    for (int e = blockIdx.x * 256 + threadIdx.x; e < NE; e += stride)
        atomicAdd(&sc[dst[e] >> 8], 1);
    __syncthreads();
    for (int i = threadIdx.x; i < NBUCK; i += 256) {
        int c = sc[i];
        if (c) atomicAdd(&bcnt[i], c);
    }
}

__global__ void k_bscan(const int* __restrict__ bcnt, int* __restrict__ bbase, int* __restrict__ bcur) {
    __shared__ int s[512];
    int t = threadIdx.x;
    int v = (t < NBUCK) ? bcnt[t] : 0;
    s[t] = v;
    __syncthreads();
    for (int off = 1; off < 512; off <<= 1) {
        int u = (t >= off) ? s[t - off] : 0;
        __syncthreads();
        s[t] += u;
        __syncthreads();
    }
    int excl = s[t] - v;
    if (t < NBUCK) { bbase[t] = excl; bcur[t] = excl; }
    if (t == 0) bbase[NBUCK] = NE;
}

__global__ __launch_bounds__(256) void k_scatterA(const int* __restrict__ src,
                                                  const int* __restrict__ dst,
                                                  int* __restrict__ bcur,
                                                  unsigned* __restrict__ scratch) {
    __shared__ uint2 sEdge[EPB];          // 25 KB
    __shared__ int cnt[512];
    __shared__ int scn[512];
    __shared__ int cntB[512];
    __shared__ int gbase[512];
    __shared__ int ssum[256];

    const int tid = threadIdx.x;
    const int ebase = blockIdx.x * EPB;

#pragma unroll
    for (int i = tid; i < 512; i += 256) { cnt[i] = 0; cntB[i] = 0; }
    __syncthreads();

    for (int i = tid; i < EPB; i += 256) {
        int b = dst[ebase + i] >> 8;
        atomicAdd(&cnt[b], 1);
    }
    __syncthreads();

    int c0 = cnt[2 * tid], c1 = cnt[2 * tid + 1];
    ssum[tid] = c0 + c1;
    __syncthreads();
    for (int off = 1; off < 256; off <<= 1) {
        int v = (tid >= off) ? ssum[tid - off] : 0;
        __syncthreads();
        ssum[tid] += v;
        __syncthreads();
    }
    int texcl = (tid == 0) ? 0 : ssum[tid - 1];
    scn[2 * tid] = texcl;
    scn[2 * tid + 1] = texcl + c0;
#pragma unroll
    for (int i = tid; i < NBUCK; i += 256) {
        int c = cnt[i];
        gbase[i] = c ? atomicAdd(&bcur[i], c) : 0;
    }
    __syncthreads();

    for (int i = tid; i < EPB; i += 256) {
        int s = src[ebase + i], d = dst[ebase + i];
        int b = d >> 8;
        int rank = atomicAdd(&cntB[b], 1);
        sEdge[scn[b] + rank] = make_uint2((unsigned)s, (unsigned)d);
    }
    __syncthreads();

    for (int i = tid; i < EPB; i += 256) {
        uint2 ed = sEdge[i];
        int b = (int)(ed.y >> 8);
        unsigned w = ((ed.y & 255u) << 24) | ed.x;
        scratch[gbase[b] + (i - scn[b])] = w;
    }
}

// per-bucket: rank by (node, src-half) -> csr rows are [lo-half edges][hi-half edges];
// emits row_ptr and the per-row split pointer.
__global__ __launch_bounds__(256) void k_fillB(const int* __restrict__ bbase,
                                               const unsigned* __restrict__ scratch,
                                               int* __restrict__ row_ptr,
                                               int* __restrict__ row_split,
                                               int* __restrict__ csr) {
    __shared__ int cnt[512];     // [node][half]
    __shared__ int cur[512];
    __shared__ int ssum[256];
    int b = blockIdx.x;
    int base = bbase[b], end = bbase[b + 1];
    int t = threadIdx.x;
    cnt[t] = 0; cnt[t + 256] = 0;
    __syncthreads();
    for (int i = base + t; i < end; i += 256) {
        unsigned w = scratch[i];
        int n = w >> 24;
        int h = (int)((w & 0xFFFFFFu) >= HALFN);
        atomicAdd(&cnt[n * 2 + h], 1);
    }
    __syncthreads();
    int c0 = cnt[2 * t], c1 = cnt[2 * t + 1];
    ssum[t] = c0 + c1;
    __syncthreads();
    for (int off = 1; off < 256; off <<= 1) {
        int u = (t >= off) ? ssum[t - off] : 0;
        __syncthreads();
        ssum[t] += u;
        __syncthreads();
    }
    int texcl = (t == 0) ? 0 : ssum[t - 1];
    int node = (b << 8) + t;
    if (node < NN) {
        row_ptr[node]   = base + texcl;
        row_split[node] = base + texcl + c0;
    }
    if (b == NBUCK - 1 && t == 0) row_ptr[NN] = NE;
    cur[2 * t] = texcl;
    cur[2 * t + 1] = texcl + c0;
    __syncthreads();
    for (int i = base + t; i < end; i += 256) {
        unsigned w = scratch[i];
        int n = w >> 24;
        int srcv = (int)(w & 0xFFFFFFu);
        int h = (int)(srcv >= HALFN);
        int p = atomicAdd(&cur[n * 2 + h], 1);
        csr[base + p] = srcv;
    }
}

// ---------------- x (row-major fp32) -> G chunk-major fp16 [4][NN][32] ----------------
__global__ __launch_bounds__(256) void k_x2h(const float* __restrict__ x, unsigned short* __restrict__ xh) {
    int j = blockIdx.x * 256 + threadIdx.x;
    int c = blockIdx.y;
    if (j >= NN) return;
    const float4* px = (const float4*)&x[(size_t)j * F + c * 32];
    unsigned short* o = &xh[((size_t)c * NN + j) * 32];
#pragma unroll
    for (int half = 0; half < 4; ++half) {
        float4 v0 = px[half * 2], v1 = px[half * 2 + 1];
        ushort8v h;
        h[0] = f2h(v0.x); h[1] = f2h(v0.y); h[2] = f2h(v0.z); h[3] = f2h(v0.w);
        h[4] = f2h(v1.x); h[5] = f2h(v1.y); h[6] = f2h(v1.z); h[7] = f2h(v1.w);
        *(ushort8v*)(o + half * 8) = h;
    }
}

// ---------------- weight: W[k][n] fp32 -> Wt [n][k] fp16 ----------------
struct WPack {
    const float* w[5];
    unsigned short* t[5];
};

__global__ void k_w2h(WPack p) {
    int which = blockIdx.x >> 6;
    int idx = (blockIdx.x & 63) * 256 + threadIdx.x; // over n*128+k
    int n = idx >> 7, k = idx & 127;
    p.t[which][idx] = f2h(p.w[which][k * 128 + n]);
}

// ---------------- unconditional accumulation over chunk column Gc[NN][32] ----------------
template <bool LOC>
__device__ __forceinline__ void accum1(float a[8], int st, int e,
                                       const int* __restrict__ sIdx,
                                       const int* __restrict__ gIdx,
                                       const unsigned short* __restrict__ Gc,
                                       int lofs) {
    int p = st;
    for (; p + 4 <= e; p += 4) {
        int j0 = LOC ? sIdx[p]     : gIdx[p];
        int j1 = LOC ? sIdx[p + 1] : gIdx[p + 1];
        int j2 = LOC ? sIdx[p + 2] : gIdx[p + 2];
        int j3 = LOC ? sIdx[p + 3] : gIdx[p + 3];
        ushort8v v0 = *(const ushort8v*)&Gc[(size_t)j0 * 32 + lofs];
        ushort8v v1 = *(const ushort8v*)&Gc[(size_t)j1 * 32 + lofs];
        ushort8v v2 = *(const ushort8v*)&Gc[(size_t)j2 * 32 + lofs];
        ushort8v v3 = *(const ushort8v*)&Gc[(size_t)j3 * 32 + lofs];
#pragma unroll
        for (int k = 0; k < 8; ++k)
            a[k] += (h2f(v0[k]) + h2f(v1[k])) + (h2f(v2[k]) + h2f(v3[k]));
    }
    for (; p < e; ++p) {
        int j0 = LOC ? sIdx[p] : gIdx[p];
        ushort8v v0 = *(const ushort8v*)&Gc[(size_t)j0 * 32 + lofs];
#pragma unroll
        for (int k = 0; k < 8; ++k) a[k] += h2f(v0[k]);
    }
}

// ---------------- aggregation: full-line chunks + half-partitioned CSR, XCD-pinned ----------------
// G layout [4][NN][32] fp16 (64B = 1 line per node per chunk).  Block class cc = h*4+c
// (bid%8 -> XCD): chunk c, src-half h.  Per-XCD working set = 50K x 64B = 3.2MB < 4MB L2.
// csr rows are pre-partitioned [lo|hi] by k_fillB: each class walks ONLY its own edges
// (no filter, no masked loads, no zero-adds).  PART[h*4+c][NN][32]; k_mlp sums halves.
__global__ __launch_bounds__(256, 8) void k_agg(const unsigned short* __restrict__ G,
                                                const int* __restrict__ row_ptr,
                                                const int* __restrict__ row_split,
                                                const int* __restrict__ csr,
                                                unsigned short* __restrict__ PART) {
    __shared__ int sRP[TROWS + 1];
    __shared__ int sSP[TROWS];
    __shared__ int sIdx[IDX_CAP];                        // 6 KB

    const int tid  = threadIdx.x;
    const int tile = blockIdx.x >> 3;
    const int cc   = blockIdx.x & 7;
    const int c    = cc & 3;
    const int hb   = cc >> 2;
    const int row0 = tile * TROWS;
    const unsigned short* Gc = G + (size_t)c * NN * 32;

    if (tid < TROWS + 1) {
        int n = row0 + tid;
        if (n > NN) n = NN;
        sRP[tid] = row_ptr[n];
    } else if (tid >= 128 && tid < 128 + TROWS) {
        int n = row0 + (tid - 128);
        sSP[tid - 128] = (n < NN) ? row_split[n] : NE;
    }
    __syncthreads();
    const int ibase = sRP[0];
    const int icnt  = sRP[TROWS] - ibase;
    const int icap  = icnt < IDX_CAP ? icnt : IDX_CAP;
    for (int i = tid; i < icap; i += 256) sIdx[i] = csr[ibase + i];
    __syncthreads();

    const int g    = tid >> 2;           // 0..63 : dst row within tile
    const int lofs = (tid & 3) * 8;      // this lane's 8 fp16 within the 32-col chunk
    const int node = row0 + g;
    if (node >= NN) return;

    float a[8] = {};
    if ((node >= HALFN) == (hb != 0)) {  // self term lives in the node's own half
        ushort8v sh = *(const ushort8v*)&Gc[(size_t)node * 32 + lofs];
#pragma unroll
        for (int k = 0; k < 8; ++k) a[k] = h2f(sh[k]);
    }

    int st, e;
    if (hb == 0) { st = sRP[g] - ibase; e = sSP[g] - ibase; }
    else         { st = sSP[g] - ibase; e = sRP[g + 1] - ibase; }
    if (e <= icap)
        accum1<true>(a, st, e, sIdx, csr + ibase, Gc, lofs);
    else
        accum1<false>(a, st, e, sIdx, csr + ibase, Gc, lofs);

    ushort8v o;
#pragma unroll
    for (int k = 0; k < 8; ++k) o[k] = f2h(a[k]);
    *(ushort8v*)&PART[((size_t)cc * NN + node) * 32 + lofs] = o;
}

// ---------------- MLP: stage (PART[0]+PART[1]) -> sA, 2-GEMM (or GEMM1+dot) ----------------
template <int L3>
__global__ __launch_bounds__(256, 6) void k_mlp(const unsigned short* __restrict__ PART,
                                                const unsigned short* __restrict__ W1,
                                                const float* __restrict__ b1,
                                                const unsigned short* __restrict__ W2,
                                                const float* __restrict__ b2,
                                                const float* __restrict__ w32,
                                                const float* __restrict__ b32,
                                                unsigned short* __restrict__ H,
                                                float* __restrict__ out) {
    __shared__ __align__(16) unsigned short sA[64 * 128];   // 16 KB

    const int tid = threadIdx.x;
    const int row0 = blockIdx.x * 64;
    const int cg   = tid >> 6;           // wave id = col slice 0..3
    const int lane = tid & 63;
    const int m16  = lane & 15;
    const int quad = lane >> 4;
    const size_t H1OFF = (size_t)4 * NN * 32;    // PART half-1 base

    // ---- stage sum of halves (chunk-major [4][NN][32]) -> swizzled sA ----
#pragma unroll
    for (int i = 0; i < 4; ++i) {
        int unit = i * 256 + tid;        // 0..1023 : 16B units
        int c    = unit >> 8;            // chunk 0..3
        int idx  = unit & 255;
        int node = idx >> 2;
        int q    = idx & 3;
        ushort8v o = {};
        if (row0 + node < NN) {
            size_t base = ((size_t)c * NN + row0 + node) * 32 + q * 8;
            ushort8v v0 = *(const ushort8v*)&PART[base];
            ushort8v v1 = *(const ushort8v*)&PART[H1OFF + base];
#pragma unroll
            for (int k = 0; k < 8; ++k) o[k] = f2h(h2f(v0[k]) + h2f(v1[k]));
        }
        int u = c * 4 + q;               // 16B-unit col 0..15
        *(ushort8v*)&sA[node * 128 + ((u ^ (node & 15)) << 3)] = o;
    }
    __syncthreads();

    // ---- GEMM1 (4 col-slice waves, 32 cols each) ----
    f32x4 acc[4][2] = {};
#pragma unroll
    for (int ks = 0; ks < 4; ++ks) {
        f16x8 a[4];
#pragma unroll
        for (int rt = 0; rt < 4; ++rt) {
            int rowL = rt * 16 + m16;
            int u = ks * 4 + quad;
            a[rt] = *(const f16x8*)&sA[rowL * 128 + ((u ^ (rowL & 15)) << 3)];
        }
#pragma unroll
        for (int ct = 0; ct < 2; ++ct) {
            int widx = (cg * 32 + ct * 16 + m16) * 128 + ks * 32 + quad * 8;
            f16x8 b = *(const f16x8*)&W1[widx];
#pragma unroll
            for (int rt = 0; rt < 4; ++rt)
                acc[rt][ct] = __builtin_amdgcn_mfma_f32_16x16x32_f16(a[rt], b, acc[rt][ct], 0, 0, 0);
        }
    }

    if (L3) {
        float* psf = (float*)sA;     // 64 rows x 4 cg
        __syncthreads();
#pragma unroll
        for (int rt = 0; rt < 4; ++rt) {
            float s[4] = {0.f, 0.f, 0.f, 0.f};
#pragma unroll
            for (int ct = 0; ct < 2; ++ct) {
                int col = cg * 32 + ct * 16 + m16;
                float bv = b1[col];
                float wv = w32[col];
#pragma unroll
                for (int i = 0; i < 4; ++i) {
                    float v = fmaxf(acc[rt][ct][i] + bv, 0.f);
                    s[i] += v * wv;
                }
            }
#pragma unroll
            for (int i = 0; i < 4; ++i) {
#pragma unroll
                for (int mask = 1; mask < 16; mask <<= 1)
                    s[i] += __shfl_xor(s[i], mask, 64);
            }
            if (m16 == 0) {
#pragma unroll
                for (int i = 0; i < 4; ++i) {
                    int rowL = rt * 16 + quad * 4 + i;
                    psf[rowL * 4 + cg] = s[i];
                }
            }
        }
        __syncthreads();
        if (tid < 64) {
            int row = row0 + tid;
            if (row < NN)
                out[row] = (psf[tid * 4] + psf[tid * 4 + 1]) + (psf[tid * 4 + 2] + psf[tid * 4 + 3]) + b32[0];
        }
        return;
    }

    // ---- h1 = relu(acc+b1) -> fp16 into LDS col-slice (C-layout -> A-layout) ----
    __syncthreads();
#pragma unroll
    for (int rt = 0; rt < 4; ++rt) {
#pragma unroll
        for (int ct = 0; ct < 2; ++ct) {
            int col = cg * 32 + ct * 16 + m16;
            float bv = b1[col];
#pragma unroll
            for (int i = 0; i < 4; ++i) {
                int rL = rt * 16 + quad * 4 + i;
                float v = fmaxf(acc[rt][ct][i] + bv, 0.f);
                sA[rL * 128 + (((col >> 3) ^ (rL & 15)) << 3) + (col & 7)] = f2h(v);
            }
        }
    }
    __syncthreads();

    // ---- GEMM2 ----
    f32x4 acc2[4][2] = {};
#pragma unroll
    for (int ks = 0; ks < 4; ++ks) {
        f16x8 a[4];
#pragma unroll
        for (int rt = 0; rt < 4; ++rt) {
            int rowL = rt * 16 + m16;
            int u = ks * 4 + quad;
            a[rt] = *(const f16x8*)&sA[rowL * 128 + ((u ^ (rowL & 15)) << 3)];
        }
#pragma unroll
        for (int ct = 0; ct < 2; ++ct) {
            int widx = (cg * 32 + ct * 16 + m16) * 128 + ks * 32 + quad * 8;
            f16x8 b = *(const f16x8*)&W2[widx];
#pragma unroll
            for (int rt = 0; rt < 4; ++rt)
                acc2[rt][ct] = __builtin_amdgcn_mfma_f32_16x16x32_f16(a[rt], b, acc2[rt][ct], 0, 0, 0);
        }
    }

    // ---- epilogue: bias -> fp16 -> LDS -> chunk-major contiguous store ----
    __syncthreads();
#pragma unroll
    for (int rt = 0; rt < 4; ++rt) {
#pragma unroll
        for (int ct = 0; ct < 2; ++ct) {
            int col = cg * 32 + ct * 16 + m16;
            float bv = b2[col];
#pragma unroll
            for (int i = 0; i < 4; ++i) {
                int rL = rt * 16 + quad * 4 + i;
                float v = acc2[rt][ct][i] + bv;
                sA[rL * 128 + (((col >> 3) ^ (rL & 15)) << 3) + (col & 7)] = f2h(v);
            }
        }
    }
    __syncthreads();
    {
#pragma unroll
        for (int i = 0; i < 4; ++i) {
            int unit = i * 256 + tid;
            int c    = unit >> 8;
            int idx  = unit & 255;
            int node = idx >> 2;
            int q    = idx & 3;
            int u    = c * 4 + q;
            if (row0 + node < NN)
                *(ushort8v*)&H[((size_t)c * NN + row0 + node) * 32 + q * 8] =
                    *(const ushort8v*)&sA[node * 128 + ((u ^ (node & 15)) << 3)];
        }
    }
}

// ---------------- launch ----------------
static inline size_t align256(size_t x) { return (x + 255) & ~(size_t)255; }

extern "C" void kernel_launch(void* const* d_in, const int* in_sizes, int n_in,
                              void* d_out, int out_size, void* d_ws, size_t ws_size,
                              hipStream_t stream) {
    const float* x   = (const float*)d_in[0];
    const int*   ei  = (const int*)d_in[1];
    const float* w11 = (const float*)d_in[2];
    const float* b11 = (const float*)d_in[3];
    const float* w12 = (const float*)d_in[4];
    const float* b12 = (const float*)d_in[5];
    const float* w21 = (const float*)d_in[6];
    const float* b21 = (const float*)d_in[7];
    const float* w22 = (const float*)d_in[8];
    const float* b22 = (const float*)d_in[9];
    const float* w31 = (const float*)d_in[10];
    const float* b31 = (const float*)d_in[11];
    const float* w32 = (const float*)d_in[12];
    const float* b32 = (const float*)d_in[13];
    float* out = (float*)d_out;

    const int* src = ei;
    const int* dst = ei + NE;

    char* ws = (char*)d_ws;
    size_t off = 0;
    unsigned short* Abuf = (unsigned short*)(ws + off); off += align256((size_t)NN * F * 2);
    unsigned short* Bbuf = (unsigned short*)(ws + off); off += align256((size_t)NN * F * 2);
    unsigned short* PART = (unsigned short*)(ws + off); off += align256((size_t)NN * F * 2 * 2);  // 2 halves
    int* bcnt      = (int*)(ws + off); off += align256((size_t)NBUCK * 4);
    int* bbase     = (int*)(ws + off); off += align256((size_t)(NBUCK + 1) * 4);
    int* bcur      = (int*)(ws + off); off += align256((size_t)NBUCK * 4);
    int* row_ptr   = (int*)(ws + off); off += align256((size_t)(NN + 1) * 4);
    int* row_split = (int*)(ws + off); off += align256((size_t)NN * 4);
    int* csr       = (int*)(ws + off); off += align256((size_t)NE * 4);
    unsigned* scratch = (unsigned*)(ws + off); off += align256((size_t)NE * 4);
    unsigned short* wt[5];
    for (int i = 0; i < 5; ++i) {
        wt[i] = (unsigned short*)(ws + off); off += align256((size_t)128 * 128 * 2);
    }
    (void)ws_size;

    // ---- weight + input conversion ----
    WPack wp;
    wp.w[0] = w11; wp.w[1] = w12; wp.w[2] = w21; wp.w[3] = w22; wp.w[4] = w31;
    for (int i = 0; i < 5; ++i) wp.t[i] = wt[i];
    k_w2h<<<320, 256, 0, stream>>>(wp);
    {
        dim3 gx((NN + 255) / 256, 4);
        k_x2h<<<gx, 256, 0, stream>>>(x, Abuf);
    }

    // ---- CSR build (bucket-level, half-partitioned rows) ----
    (void)hipMemsetAsync(bcnt, 0, (size_t)NBUCK * 4, stream);
    k_bhist<<<512, 256, 0, stream>>>(dst, bcnt);
    k_bscan<<<1, 512, 0, stream>>>(bcnt, bbase, bcur);
    k_scatterA<<<SCAT_BLOCKS, 256, 0, stream>>>(src, dst, bcur, scratch);
    k_fillB<<<NBUCK, 256, 0, stream>>>(bbase, scratch, row_ptr, row_split, csr);

    const int mlpTiles = (NN + 63) / 64;        // 1563
    const int aggBlocks = NTILE * 8;            // 12504, bid%8 = class -> XCD

    // ---- layer 1: Abuf -> PART -> Bbuf ----
    k_agg<<<aggBlocks, 256, 0, stream>>>(Abuf, row_ptr, row_split, csr, PART);
    k_mlp<0><<<mlpTiles, 256, 0, stream>>>(PART, wt[0], b11, wt[1], b12,
                                           nullptr, nullptr, Bbuf, nullptr);
    // ---- layer 2: Bbuf -> PART -> Abuf ----
    k_agg<<<aggBlocks, 256, 0, stream>>>(Bbuf, row_ptr, row_split, csr, PART);
    k_mlp<0><<<mlpTiles, 256, 0, stream>>>(PART, wt[2], b21, wt[3], b22,
                                           nullptr, nullptr, Abuf, nullptr);
    // ---- layer 3: Abuf -> PART -> out ----
    k_agg<<<aggBlocks, 256, 0, stream>>>(Abuf, row_ptr, row_split, csr, PART);
    k_mlp<1><<<mlpTiles, 256, 0, stream>>>(PART, wt[4], b31, nullptr, nullptr,
                                           w32, b32, nullptr, out);
}

// Round 7
// 416.207 us; speedup vs baseline: 1.3160x; 1.0400x over previous
//
#include <hip/hip_runtime.h>

#define NN 100000
#define NE 1600000
#define F 128
#define HALFN 50000
#define NBUCK ((NN + 255) >> 8)                         // 391 buckets of 256 nodes
#define SCAT_BLOCKS 512
#define EPB (NE / SCAT_BLOCKS)                          // 3125 edges per scatter block
#define TROWS 64                                        // dst rows per k_agg tile
#define NTILE ((NN + TROWS - 1) / TROWS)                // 1563
#define IDX_CAP 1024                                    // per-half slice: mean 512, sd ~23

typedef _Float16 f16x8 __attribute__((ext_vector_type(8)));
typedef _Float16 half8v __attribute__((ext_vector_type(8)));
typedef float    f32x4 __attribute__((ext_vector_type(4)));
typedef float    float8v __attribute__((ext_vector_type(8)));
typedef unsigned short ushort8v __attribute__((ext_vector_type(8)));

__device__ inline unsigned short f2h(float f) {
    _Float16 h = (_Float16)f;                       // RTN
    return __builtin_bit_cast(unsigned short, h);
}
__device__ inline float h2f(unsigned short u) {
    return (float)__builtin_bit_cast(_Float16, u);
}

// ---------------- CSR build (bucket-level binning, split by src-half) ----------------
// counts per (bucket, src-half)
__global__ __launch_bounds__(256) void k_bhist(const int* __restrict__ src,
                                               const int* __restrict__ dst,
                                               int* __restrict__ bcnt2) {
    __shared__ int sc[NBUCK * 2];
    for (int i = threadIdx.x; i < NBUCK * 2; i += 256) sc[i] = 0;
    __syncthreads();
    int stride = gridDim.x * 256;
    for (int e = blockIdx.x * 256 + threadIdx.x; e < NE; e += stride) {
        int b = dst[e] >> 8;
        int h = (int)(src[e] >= HALFN);
        atomicAdd(&sc[b * 2 + h], 1);
    }
    __syncthreads();
    for (int i = threadIdx.x; i < NBUCK * 2; i += 256) {
        int c = sc[i];
        if (c) atomicAdd(&bcnt2[i], c);
    }
}

// two 512-wide scans (L and H); bucket totals (L+H) feed the scratch layout.
__global__ void k_bscan(const int* __restrict__ bcnt2,
                        int* __restrict__ bbaseL, int* __restrict__ bbaseH,
                        int* __restrict__ bbase, int* __restrict__ bcur) {
    __shared__ int s[512];
    int t = threadIdx.x;
    int vL = (t < NBUCK) ? bcnt2[2 * t] : 0;
    int vH = (t < NBUCK) ? bcnt2[2 * t + 1] : 0;
    s[t] = vL;
    __syncthreads();
    for (int off = 1; off < 512; off <<= 1) {
        int u = (t >= off) ? s[t - off] : 0;
        __syncthreads();
        s[t] += u;
        __syncthreads();
    }
    int incL = s[t];
    __syncthreads();
    s[t] = vH;
    __syncthreads();
    for (int off = 1; off < 512; off <<= 1) {
        int u = (t >= off) ? s[t - off] : 0;
        __syncthreads();
        s[t] += u;
        __syncthreads();
    }
    int incH = s[t];
    int exL = incL - vL, exH = incH - vH;
    if (t < NBUCK) {
        bbaseL[t] = exL;
        bbaseH[t] = exH;
        bbase[t] = exL + exH;
        bcur[t] = exL + exH;
    }
    if (t == NBUCK - 1) {
        bbaseL[NBUCK] = incL;
        bbaseH[NBUCK] = incH;
        bbase[NBUCK] = incL + incH;
    }
}

__global__ __launch_bounds__(256) void k_scatterA(const int* __restrict__ src,
                                                  const int* __restrict__ dst,
                                                  int* __restrict__ bcur,
                                                  unsigned* __restrict__ scratch) {
    __shared__ uint2 sEdge[EPB];          // 25 KB
    __shared__ int cnt[512];
    __shared__ int scn[512];
    __shared__ int cntB[512];
    __shared__ int gbase[512];
    __shared__ int ssum[256];

    const int tid = threadIdx.x;
    const int ebase = blockIdx.x * EPB;

#pragma unroll
    for (int i = tid; i < 512; i += 256) { cnt[i] = 0; cntB[i] = 0; }
    __syncthreads();

    for (int i = tid; i < EPB; i += 256) {
        int b = dst[ebase + i] >> 8;
        atomicAdd(&cnt[b], 1);
    }
    __syncthreads();

    int c0 = cnt[2 * tid], c1 = cnt[2 * tid + 1];
    ssum[tid] = c0 + c1;
    __syncthreads();
    for (int off = 1; off < 256; off <<= 1) {
        int v = (tid >= off) ? ssum[tid - off] : 0;
        __syncthreads();
        ssum[tid] += v;
        __syncthreads();
    }
    int texcl = (tid == 0) ? 0 : ssum[tid - 1];
    scn[2 * tid] = texcl;
    scn[2 * tid + 1] = texcl + c0;
#pragma unroll
    for (int i = tid; i < NBUCK; i += 256) {
        int c = cnt[i];
        gbase[i] = c ? atomicAdd(&bcur[i], c) : 0;
    }
    __syncthreads();

    for (int i = tid; i < EPB; i += 256) {
        int s = src[ebase + i], d = dst[ebase + i];
        int b = d >> 8;
        int rank = atomicAdd(&cntB[b], 1);
        sEdge[scn[b] + rank] = make_uint2((unsigned)s, (unsigned)d);
    }
    __syncthreads();

    for (int i = tid; i < EPB; i += 256) {
        uint2 ed = sEdge[i];
        int b = (int)(ed.y >> 8);
        unsigned w = ((ed.y & 255u) << 24) | ed.x;
        scratch[gbase[b] + (i - scn[b])] = w;
    }
}

// per-bucket: rank by (node, half) -> separate csrL / csrH arrays, each globally
// contiguous by node (row_ptrL/H are proper CSRs over them).
__global__ __launch_bounds__(256) void k_fillB(const int* __restrict__ bbase,
                                               const int* __restrict__ bbaseL,
                                               const int* __restrict__ bbaseH,
                                               const unsigned* __restrict__ scratch,
                                               int* __restrict__ row_ptrL,
                                               int* __restrict__ row_ptrH,
                                               int* __restrict__ csrL,
                                               int* __restrict__ csrH) {
    __shared__ int cnt[512];     // [node][half], reused as cur
    __shared__ int sA[256];
    __shared__ int sB[256];
    int b = blockIdx.x;
    int base = bbase[b], end = bbase[b + 1];
    int t = threadIdx.x;
    cnt[t] = 0; cnt[t + 256] = 0;
    __syncthreads();
    for (int i = base + t; i < end; i += 256) {
        unsigned w = scratch[i];
        int n = w >> 24;
        int h = (int)((w & 0xFFFFFFu) >= HALFN);
        atomicAdd(&cnt[n * 2 + h], 1);
    }
    __syncthreads();
    int c0 = cnt[2 * t], c1 = cnt[2 * t + 1];
    sA[t] = c0; sB[t] = c1;
    __syncthreads();
    for (int off = 1; off < 256; off <<= 1) {
        int uA = (t >= off) ? sA[t - off] : 0;
        int uB = (t >= off) ? sB[t - off] : 0;
        __syncthreads();
        sA[t] += uA; sB[t] += uB;
        __syncthreads();
    }
    int exL = sA[t] - c0, exH = sB[t] - c1;
    int node = (b << 8) + t;
    if (node < NN) {
        row_ptrL[node] = bbaseL[b] + exL;
        row_ptrH[node] = bbaseH[b] + exH;
    }
    if (b == NBUCK - 1 && t == 0) {
        row_ptrL[NN] = bbaseL[NBUCK];
        row_ptrH[NN] = bbaseH[NBUCK];
    }
    cnt[2 * t] = exL; cnt[2 * t + 1] = exH;
    __syncthreads();
    for (int i = base + t; i < end; i += 256) {
        unsigned w = scratch[i];
        int n = w >> 24;
        int srcv = (int)(w & 0xFFFFFFu);
        int h = (int)(srcv >= HALFN);
        int p = atomicAdd(&cnt[n * 2 + h], 1);
        if (h) csrH[bbaseH[b] + p] = srcv;
        else   csrL[bbaseL[b] + p] = srcv;
    }
}

// ---------------- x (row-major fp32) -> G chunk-major fp16 [4][NN][32] ----------------
__global__ __launch_bounds__(256) void k_x2h(const float* __restrict__ x, unsigned short* __restrict__ xh) {
    int j = blockIdx.x * 256 + threadIdx.x;
    int c = blockIdx.y;
    if (j >= NN) return;
    const float4* px = (const float4*)&x[(size_t)j * F + c * 32];
    unsigned short* o = &xh[((size_t)c * NN + j) * 32];
#pragma unroll
    for (int half = 0; half < 4; ++half) {
        float4 v0 = px[half * 2], v1 = px[half * 2 + 1];
        ushort8v h;
        h[0] = f2h(v0.x); h[1] = f2h(v0.y); h[2] = f2h(v0.z); h[3] = f2h(v0.w);
        h[4] = f2h(v1.x); h[5] = f2h(v1.y); h[6] = f2h(v1.z); h[7] = f2h(v1.w);
        *(ushort8v*)(o + half * 8) = h;
    }
}

// ---------------- weight: W[k][n] fp32 -> Wt [n][k] fp16 ----------------
struct WPack {
    const float* w[5];
    unsigned short* t[5];
};

__global__ void k_w2h(WPack p) {
    int which = blockIdx.x >> 6;
    int idx = (blockIdx.x & 63) * 256 + threadIdx.x; // over n*128+k
    int n = idx >> 7, k = idx & 127;
    p.t[which][idx] = f2h(p.w[which][k * 128 + n]);
}

// ---------------- vectorized accumulation over chunk column Gc[NN][32] ----------------
template <bool LOC>
__device__ __forceinline__ void accum1(float8v& a, int st, int e,
                                       const int* __restrict__ sIdx,
                                       const int* __restrict__ gIdx,
                                       const unsigned short* __restrict__ Gc,
                                       int lofs) {
    int p = st;
    for (; p + 4 <= e; p += 4) {
        int j0 = LOC ? sIdx[p]     : gIdx[p];
        int j1 = LOC ? sIdx[p + 1] : gIdx[p + 1];
        int j2 = LOC ? sIdx[p + 2] : gIdx[p + 2];
        int j3 = LOC ? sIdx[p + 3] : gIdx[p + 3];
        half8v v0 = *(const half8v*)&Gc[(size_t)j0 * 32 + lofs];
        half8v v1 = *(const half8v*)&Gc[(size_t)j1 * 32 + lofs];
        half8v v2 = *(const half8v*)&Gc[(size_t)j2 * 32 + lofs];
        half8v v3 = *(const half8v*)&Gc[(size_t)j3 * 32 + lofs];
        float8v f0 = __builtin_convertvector(v0, float8v);
        float8v f1 = __builtin_convertvector(v1, float8v);
        float8v f2 = __builtin_convertvector(v2, float8v);
        float8v f3 = __builtin_convertvector(v3, float8v);
        a += (f0 + f1) + (f2 + f3);
    }
    for (; p < e; ++p) {
        int j0 = LOC ? sIdx[p] : gIdx[p];
        half8v v0 = *(const half8v*)&Gc[(size_t)j0 * 32 + lofs];
        a += __builtin_convertvector(v0, float8v);
    }
}

// ---------------- aggregation: full-line chunks + split CSR, XCD-pinned ----------------
// G layout [4][NN][32] fp16 (64B = 1 line per node per chunk).  Block class cc = h*4+c
// (bid%8 -> XCD): chunk c, src-half h; per-XCD feature working set 3.2MB < 4MB L2.
// csrL/csrH are physically separate: each class stages ONLY its own edges
// (csr stream per XCD halves to 3.2MB).  PART[cc][NN][32]; k_mlp sums halves.
__global__ __launch_bounds__(256, 8) void k_agg(const unsigned short* __restrict__ G,
                                                const int* __restrict__ row_ptrL,
                                                const int* __restrict__ row_ptrH,
                                                const int* __restrict__ csrL,
                                                const int* __restrict__ csrH,
                                                unsigned short* __restrict__ PART) {
    __shared__ int sRP[TROWS + 1];
    __shared__ int sIdx[IDX_CAP];                        // 4 KB

    const int tid  = threadIdx.x;
    const int tile = blockIdx.x >> 3;
    const int cc   = blockIdx.x & 7;
    const int c    = cc & 3;
    const int hb   = cc >> 2;
    const int row0 = tile * TROWS;
    const unsigned short* Gc = G + (size_t)c * NN * 32;
    const int* __restrict__ rp = hb ? row_ptrH : row_ptrL;
    const int* __restrict__ cs = hb ? csrH : csrL;

    if (tid < TROWS + 1) {
        int n = row0 + tid;
        if (n > NN) n = NN;
        sRP[tid] = rp[n];
    }
    __syncthreads();
    const int ibase = sRP[0];
    const int icnt  = sRP[TROWS] - ibase;
    const int icap  = icnt < IDX_CAP ? icnt : IDX_CAP;
    for (int i = tid; i < icap; i += 256) sIdx[i] = cs[ibase + i];
    __syncthreads();

    const int g    = tid >> 2;           // 0..63 : dst row within tile
    const int lofs = (tid & 3) * 8;      // this lane's 8 fp16 within the 32-col chunk
    const int node = row0 + g;
    if (node >= NN) return;

    float8v a = {};
    if ((node >= HALFN) == (hb != 0)) {  // self term lives in the node's own half
        half8v sh = *(const half8v*)&Gc[(size_t)node * 32 + lofs];
        a = __builtin_convertvector(sh, float8v);
    }

    int st = sRP[g] - ibase, e = sRP[g + 1] - ibase;
    if (e <= icap)
        accum1<true>(a, st, e, sIdx, cs + ibase, Gc, lofs);
    else
        accum1<false>(a, st, e, sIdx, cs + ibase, Gc, lofs);

    half8v o = __builtin_convertvector(a, half8v);
    *(half8v*)&PART[((size_t)cc * NN + node) * 32 + lofs] = o;
}

// ---------------- MLP: stage (PART lo + hi) -> sA, 2-GEMM (or GEMM1+dot) ----------------
template <int L3>
__global__ __launch_bounds__(256, 6) void k_mlp(const unsigned short* __restrict__ PART,
                                                const unsigned short* __restrict__ W1,
                                                const float* __restrict__ b1,
                                                const unsigned short* __restrict__ W2,
                                                const float* __restrict__ b2,
                                                const float* __restrict__ w32,
                                                const float* __restrict__ b32,
                                                unsigned short* __restrict__ H,
                                                float* __restrict__ out) {
    __shared__ __align__(16) unsigned short sA[64 * 128];   // 16 KB

    const int tid = threadIdx.x;
    const int row0 = blockIdx.x * 64;
    const int cg   = tid >> 6;           // wave id = col slice 0..3
    const int lane = tid & 63;
    const int m16  = lane & 15;
    const int quad = lane >> 4;
    const size_t H1OFF = (size_t)4 * NN * 32;    // PART half-1 base

    // ---- stage sum of halves (chunk-major [4][NN][32]) -> swizzled sA ----
#pragma unroll
    for (int i = 0; i < 4; ++i) {
        int unit = i * 256 + tid;        // 0..1023 : 16B units
        int c    = unit >> 8;            // chunk 0..3
        int idx  = unit & 255;
        int node = idx >> 2;
        int q    = idx & 3;
        half8v o = {};
        if (row0 + node < NN) {
            size_t base = ((size_t)c * NN + row0 + node) * 32 + q * 8;
            half8v v0 = *(const half8v*)&PART[base];
            half8v v1 = *(const half8v*)&PART[H1OFF + base];
            float8v s = __builtin_convertvector(v0, float8v) + __builtin_convertvector(v1, float8v);
            o = __builtin_convertvector(s, half8v);
        }
        int u = c * 4 + q;               // 16B-unit col 0..15
        *(half8v*)&sA[node * 128 + ((u ^ (node & 15)) << 3)] = o;
    }
    __syncthreads();

    // ---- GEMM1 (4 col-slice waves, 32 cols each) ----
    f32x4 acc[4][2] = {};
#pragma unroll
    for (int ks = 0; ks < 4; ++ks) {
        f16x8 a[4];
#pragma unroll
        for (int rt = 0; rt < 4; ++rt) {
            int rowL = rt * 16 + m16;
            int u = ks * 4 + quad;
            a[rt] = *(const f16x8*)&sA[rowL * 128 + ((u ^ (rowL & 15)) << 3)];
        }
#pragma unroll
        for (int ct = 0; ct < 2; ++ct) {
            int widx = (cg * 32 + ct * 16 + m16) * 128 + ks * 32 + quad * 8;
            f16x8 b = *(const f16x8*)&W1[widx];
#pragma unroll
            for (int rt = 0; rt < 4; ++rt)
                acc[rt][ct] = __builtin_amdgcn_mfma_f32_16x16x32_f16(a[rt], b, acc[rt][ct], 0, 0, 0);
        }
    }

    if (L3) {
        float* psf = (float*)sA;     // 64 rows x 4 cg
        __syncthreads();
#pragma unroll
        for (int rt = 0; rt < 4; ++rt) {
            float s[4] = {0.f, 0.f, 0.f, 0.f};
#pragma unroll
            for (int ct = 0; ct < 2; ++ct) {
                int col = cg * 32 + ct * 16 + m16;
                float bv = b1[col];
                float wv = w32[col];
#pragma unroll
                for (int i = 0; i < 4; ++i) {
                    float v = fmaxf(acc[rt][ct][i] + bv, 0.f);
                    s[i] += v * wv;
                }
            }
#pragma unroll
            for (int i = 0; i < 4; ++i) {
#pragma unroll
                for (int mask = 1; mask < 16; mask <<= 1)
                    s[i] += __shfl_xor(s[i], mask, 64);
            }
            if (m16 == 0) {
#pragma unroll
                for (int i = 0; i < 4; ++i) {
                    int rowL = rt * 16 + quad * 4 + i;
                    psf[rowL * 4 + cg] = s[i];
                }
            }
        }
        __syncthreads();
        if (tid < 64) {
            int row = row0 + tid;
            if (row < NN)
                out[row] = (psf[tid * 4] + psf[tid * 4 + 1]) + (psf[tid * 4 + 2] + psf[tid * 4 + 3]) + b32[0];
        }
        return;
    }

    // ---- h1 = relu(acc+b1) -> fp16 into LDS col-slice (C-layout -> A-layout) ----
    __syncthreads();
#pragma unroll
    for (int rt = 0; rt < 4; ++rt) {
#pragma unroll
        for (int ct = 0; ct < 2; ++ct) {
            int col = cg * 32 + ct * 16 + m16;
            float bv = b1[col];
#pragma unroll
            for (int i = 0; i < 4; ++i) {
                int rL = rt * 16 + quad * 4 + i;
                float v = fmaxf(acc[rt][ct][i] + bv, 0.f);
                sA[rL * 128 + (((col >> 3) ^ (rL & 15)) << 3) + (col & 7)] = f2h(v);
            }
        }
    }
    __syncthreads();

    // ---- GEMM2 ----
    f32x4 acc2[4][2] = {};
#pragma unroll
    for (int ks = 0; ks < 4; ++ks) {
        f16x8 a[4];
#pragma unroll
        for (int rt = 0; rt < 4; ++rt) {
            int rowL = rt * 16 + m16;
            int u = ks * 4 + quad;
            a[rt] = *(const f16x8*)&sA[rowL * 128 + ((u ^ (rowL & 15)) << 3)];
        }
#pragma unroll
        for (int ct = 0; ct < 2; ++ct) {
            int widx = (cg * 32 + ct * 16 + m16) * 128 + ks * 32 + quad * 8;
            f16x8 b = *(const f16x8*)&W2[widx];
#pragma unroll
            for (int rt = 0; rt < 4; ++rt)
                acc2[rt][ct] = __builtin_amdgcn_mfma_f32_16x16x32_f16(a[rt], b, acc2[rt][ct], 0, 0, 0);
        }
    }

    // ---- epilogue: bias -> fp16 -> LDS -> chunk-major contiguous store ----
    __syncthreads();
#pragma unroll
    for (int rt = 0; rt < 4; ++rt) {
#pragma unroll
        for (int ct = 0; ct < 2; ++ct) {
            int col = cg * 32 + ct * 16 + m16;
            float bv = b2[col];
#pragma unroll
            for (int i = 0; i < 4; ++i) {
                int rL = rt * 16 + quad * 4 + i;
                float v = acc2[rt][ct][i] + bv;
                sA[rL * 128 + (((col >> 3) ^ (rL & 15)) << 3) + (col & 7)] = f2h(v);
            }
        }
    }
    __syncthreads();
    {
#pragma unroll
        for (int i = 0; i < 4; ++i) {
            int unit = i * 256 + tid;
            int c    = unit >> 8;
            int idx  = unit & 255;
            int node = idx >> 2;
            int q    = idx & 3;
            int u    = c * 4 + q;
            if (row0 + node < NN)
                *(ushort8v*)&H[((size_t)c * NN + row0 + node) * 32 + q * 8] =
                    *(const ushort8v*)&sA[node * 128 + ((u ^ (node & 15)) << 3)];
        }
    }
}

// ---------------- launch ----------------
static inline size_t align256(size_t x) { return (x + 255) & ~(size_t)255; }

extern "C" void kernel_launch(void* const* d_in, const int* in_sizes, int n_in,
                              void* d_out, int out_size, void* d_ws, size_t ws_size,
                              hipStream_t stream) {
    const float* x   = (const float*)d_in[0];
    const int*   ei  = (const int*)d_in[1];
    const float* w11 = (const float*)d_in[2];
    const float* b11 = (const float*)d_in[3];
    const float* w12 = (const float*)d_in[4];
    const float* b12 = (const float*)d_in[5];
    const float* w21 = (const float*)d_in[6];
    const float* b21 = (const float*)d_in[7];
    const float* w22 = (const float*)d_in[8];
    const float* b22 = (const float*)d_in[9];
    const float* w31 = (const float*)d_in[10];
    const float* b31 = (const float*)d_in[11];
    const float* w32 = (const float*)d_in[12];
    const float* b32 = (const float*)d_in[13];
    float* out = (float*)d_out;

    const int* src = ei;
    const int* dst = ei + NE;

    char* ws = (char*)d_ws;
    size_t off = 0;
    unsigned short* Abuf = (unsigned short*)(ws + off); off += align256((size_t)NN * F * 2);
    unsigned short* Bbuf = (unsigned short*)(ws + off); off += align256((size_t)NN * F * 2);
    unsigned short* PART = (unsigned short*)(ws + off); off += align256((size_t)NN * F * 2 * 2);  // 2 halves
    int* bcnt2   = (int*)(ws + off); off += align256((size_t)NBUCK * 2 * 4);
    int* bbaseL  = (int*)(ws + off); off += align256((size_t)(NBUCK + 1) * 4);
    int* bbaseH  = (int*)(ws + off); off += align256((size_t)(NBUCK + 1) * 4);
    int* bbase   = (int*)(ws + off); off += align256((size_t)(NBUCK + 1) * 4);
    int* bcur    = (int*)(ws + off); off += align256((size_t)NBUCK * 4);
    int* row_ptrL = (int*)(ws + off); off += align256((size_t)(NN + 1) * 4);
    int* row_ptrH = (int*)(ws + off); off += align256((size_t)(NN + 1) * 4);
    int* csrL    = (int*)(ws + off); off += align256((size_t)NE * 4);
    int* csrH    = (int*)(ws + off); off += align256((size_t)NE * 4);
    unsigned* scratch = (unsigned*)(ws + off); off += align256((size_t)NE * 4);
    unsigned short* wt[5];
    for (int i = 0; i < 5; ++i) {
        wt[i] = (unsigned short*)(ws + off); off += align256((size_t)128 * 128 * 2);
    }
    (void)ws_size;

    // ---- weight + input conversion ----
    WPack wp;
    wp.w[0] = w11; wp.w[1] = w12; wp.w[2] = w21; wp.w[3] = w22; wp.w[4] = w31;
    for (int i = 0; i < 5; ++i) wp.t[i] = wt[i];
    k_w2h<<<320, 256, 0, stream>>>(wp);
    {
        dim3 gx((NN + 255) / 256, 4);
        k_x2h<<<gx, 256, 0, stream>>>(x, Abuf);
    }

    // ---- CSR build (bucket-level, physically split by src-half) ----
    (void)hipMemsetAsync(bcnt2, 0, (size_t)NBUCK * 2 * 4, stream);
    k_bhist<<<512, 256, 0, stream>>>(src, dst, bcnt2);
    k_bscan<<<1, 512, 0, stream>>>(bcnt2, bbaseL, bbaseH, bbase, bcur);
    k_scatterA<<<SCAT_BLOCKS, 256, 0, stream>>>(src, dst, bcur, scratch);
    k_fillB<<<NBUCK, 256, 0, stream>>>(bbase, bbaseL, bbaseH, scratch,
                                       row_ptrL, row_ptrH, csrL, csrH);

    const int mlpTiles = (NN + 63) / 64;        // 1563
    const int aggBlocks = NTILE * 8;            // 12504, bid%8 = class -> XCD

    // ---- layer 1: Abuf -> PART -> Bbuf ----
    k_agg<<<aggBlocks, 256, 0, stream>>>(Abuf, row_ptrL, row_ptrH, csrL, csrH, PART);
    k_mlp<0><<<mlpTiles, 256, 0, stream>>>(PART, wt[0], b11, wt[1], b12,
                                           nullptr, nullptr, Bbuf, nullptr);
    // ---- layer 2: Bbuf -> PART -> Abuf ----
    k_agg<<<aggBlocks, 256, 0, stream>>>(Bbuf, row_ptrL, row_ptrH, csrL, csrH, PART);
    k_mlp<0><<<mlpTiles, 256, 0, stream>>>(PART, wt[2], b21, wt[3], b22,
                                           nullptr, nullptr, Abuf, nullptr);
    // ---- layer 3: Abuf -> PART -> out ----
    k_agg<<<aggBlocks, 256, 0, stream>>>(Abuf, row_ptrL, row_ptrH, csrL, csrH, PART);
    k_mlp<1><<<mlpTiles, 256, 0, stream>>>(PART, wt[4], b31, nullptr, nullptr,
                                           w32, b32, nullptr, out);
}